// Round 1
// baseline (1105.609 us; speedup 1.0000x reference)
//
#include <hip/hip_runtime.h>
#include <hip/hip_bf16.h>
#include <math.h>

#define NN   4096
#define EE   131072
#define HH   4
#define DIN  128
#define DH   256
#define DCAT 1024   /* HH*DH */
#define ALPHA_LR 0.2f

// ------------------------------------------------------------------
// Tiled fp32 GEMM: C[z][M][ldc] = act(A[M][lda] @ B[z][K][ldb] + bias)
// block 256 threads, 64x64 tile, 4x4 per thread.
// ------------------------------------------------------------------
__global__ void gemm_kernel(const float* __restrict__ A, int lda,
                            const float* __restrict__ B, long strideB, int ldb,
                            float* __restrict__ C, long strideC, int ldc,
                            int K, const float* __restrict__ bias, int relu_act)
{
    __shared__ float sA[64][17];
    __shared__ float sB[16][64];
    const float* Bz = B + (long)blockIdx.z * strideB;
    float* Cz = C + (long)blockIdx.z * strideC;
    int tid = threadIdx.x;
    int tx = tid & 15, ty = tid >> 4;
    int row0 = blockIdx.x * 64;
    int col0 = blockIdx.y * 64;
    float acc[4][4] = {};
    for (int k0 = 0; k0 < K; k0 += 16) {
        for (int i = tid; i < 64 * 16; i += 256) {
            int m = i >> 4, k = i & 15;
            sA[m][k] = A[(long)(row0 + m) * lda + k0 + k];
        }
        for (int i = tid; i < 16 * 64; i += 256) {
            int k = i >> 6, n = i & 63;
            sB[k][n] = Bz[(long)(k0 + k) * ldb + col0 + n];
        }
        __syncthreads();
#pragma unroll
        for (int k = 0; k < 16; ++k) {
            float a[4], b[4];
#pragma unroll
            for (int i = 0; i < 4; ++i) a[i] = sA[ty + 16 * i][k];
#pragma unroll
            for (int j = 0; j < 4; ++j) b[j] = sB[k][tx + 16 * j];
#pragma unroll
            for (int i = 0; i < 4; ++i)
#pragma unroll
                for (int j = 0; j < 4; ++j)
                    acc[i][j] = fmaf(a[i], b[j], acc[i][j]);
        }
        __syncthreads();
    }
#pragma unroll
    for (int i = 0; i < 4; ++i) {
        int r = row0 + ty + 16 * i;
#pragma unroll
        for (int j = 0; j < 4; ++j) {
            int c = col0 + tx + 16 * j;
            float v = acc[i][j];
            if (bias) v += bias[c];
            if (relu_act) v = v > 0.f ? v : 0.f;
            Cz[(long)r * ldc + c] = v;
        }
    }
}

// ------------------------------------------------------------------
// e_src / e_dst: per (h,n) row dot with attention vector halves.
// One 64-lane wave per row; 4 waves per block.
// ------------------------------------------------------------------
__global__ void attvec_kernel(const float* __restrict__ Wh, const float* __restrict__ a,
                              float* __restrict__ es, float* __restrict__ ed)
{
    int wave = threadIdx.x >> 6, lane = threadIdx.x & 63;
    int idx = blockIdx.x * 4 + wave;       // idx = h*NN + n
    int h = idx >> 12;
    const float* row = Wh + (long)idx * DH;
    const float* ah = a + h * (2 * DH);
    float s1 = 0.f, s2 = 0.f;
#pragma unroll
    for (int o = lane; o < DH; o += 64) {
        float w = row[o];
        s1 = fmaf(ah[o], w, s1);
        s2 = fmaf(ah[DH + o], w, s2);
    }
#pragma unroll
    for (int off = 32; off; off >>= 1) {
        s1 += __shfl_down(s1, off);
        s2 += __shfl_down(s2, off);
    }
    if (lane == 0) { es[idx] = s1; ed[idx] = s2; }
}

// ------------------------------------------------------------------
// Per-edge: w = exp(leaky_relu(es+ed)) - 1 ; accumulate denominators.
// ------------------------------------------------------------------
__global__ void edge_kernel(const int* __restrict__ src, const int* __restrict__ dst,
                            const float* __restrict__ es, const float* __restrict__ ed,
                            float* __restrict__ wmin, float* __restrict__ dacc)
{
    int e = blockIdx.x * 256 + threadIdx.x;
    int s = src[e], d = dst[e];
#pragma unroll
    for (int h = 0; h < HH; ++h) {
        float v = es[h * NN + s] + ed[h * NN + d];
        v = v > 0.f ? v : ALPHA_LR * v;
        float w = expm1f(v);
        wmin[h * EE + e] = w;
        atomicAdd(&dacc[h * NN + s], w);
    }
}

__global__ void denom_kernel(const float* __restrict__ dacc, float* __restrict__ invd)
{
    int i = blockIdx.x * 256 + threadIdx.x;
    invd[i] = 1.f / ((float)NN + dacc[i]);
}

// reduce sum of v[0..n) into *out (accumulating across layers)
__global__ void reduce_add_kernel(const float* __restrict__ v, int n, float* __restrict__ out)
{
    float s = 0.f;
    for (int i = blockIdx.x * blockDim.x + threadIdx.x; i < n; i += gridDim.x * blockDim.x)
        s += v[i];
#pragma unroll
    for (int off = 32; off; off >>= 1) s += __shfl_down(s, off);
    __shared__ float red[4];
    if ((threadIdx.x & 63) == 0) red[threadIdx.x >> 6] = s;
    __syncthreads();
    if (threadIdx.x == 0) atomicAdd(out, red[0] + red[1] + red[2] + red[3]);
}

// importance scatter: imp[dst] += sum_h w*invd[h,src]
__global__ void imp_kernel(const int* __restrict__ src, const int* __restrict__ dst,
                           const float* __restrict__ wmin, const float* __restrict__ invd,
                           float* __restrict__ imp)
{
    int e = blockIdx.x * 256 + threadIdx.x;
    int s = src[e], d = dst[e];
    float t = wmin[e] * invd[s]
            + wmin[EE + e] * invd[NN + s]
            + wmin[2 * EE + e] * invd[2 * NN + s]
            + wmin[3 * EE + e] * invd[3 * NN + s];
    atomicAdd(&imp[d], t);
}

// column sums of Wh per head
__global__ void colsum_kernel(const float* __restrict__ Wh, float* __restrict__ csum)
{
    int h = blockIdx.x >> 4;
    int chunk = blockIdx.x & 15;
    int o = threadIdx.x;
    float s = 0.f;
    for (int n = chunk * 256; n < chunk * 256 + 256; ++n)
        s += Wh[((long)h * NN + n) * DH + o];
    atomicAdd(&csum[h * DH + o], s);
}

// ------------------------------------------------------------------
// CSR build
// ------------------------------------------------------------------
__global__ void count_kernel(const int* __restrict__ src, int* __restrict__ counts)
{
    int e = blockIdx.x * 256 + threadIdx.x;
    atomicAdd(&counts[src[e]], 1);
}

__global__ void scan_kernel(const int* __restrict__ counts, int* __restrict__ rowptr)
{
    __shared__ int lsum[1024];
    int t = threadIdx.x;
    int base = t * 4;
    int c0 = counts[base], c1 = counts[base + 1], c2 = counts[base + 2], c3 = counts[base + 3];
    int s = c0 + c1 + c2 + c3;
    lsum[t] = s;
    __syncthreads();
    for (int off = 1; off < 1024; off <<= 1) {
        int v = (t >= off) ? lsum[t - off] : 0;
        __syncthreads();
        lsum[t] += v;
        __syncthreads();
    }
    int excl = lsum[t] - s;
    rowptr[base] = excl;
    rowptr[base + 1] = excl + c0;
    rowptr[base + 2] = excl + c0 + c1;
    rowptr[base + 3] = excl + c0 + c1 + c2;
    if (t == 1023) rowptr[NN] = lsum[1023];
}

__global__ void copy_int_kernel(const int* __restrict__ a, int* __restrict__ b, int n)
{
    int i = blockIdx.x * 256 + threadIdx.x;
    if (i < n) b[i] = a[i];
}

__global__ void fill_kernel(const int* __restrict__ src, const int* __restrict__ dst,
                            int* __restrict__ cursor, int* __restrict__ cdst,
                            int* __restrict__ ceid)
{
    int e = blockIdx.x * 256 + threadIdx.x;
    int s = src[e];
    int pos = atomicAdd(&cursor[s], 1);
    cdst[pos] = dst[e];
    ceid[pos] = e;
}

// ------------------------------------------------------------------
// Aggregation: block per node n, thread per output o; 4 head accums.
// ------------------------------------------------------------------
__global__ void agg_kernel(const float* __restrict__ Wh, const float* __restrict__ wmin,
                           const float* __restrict__ invd, const float* __restrict__ csum,
                           const int* __restrict__ rowptr, const int* __restrict__ cdst,
                           const int* __restrict__ ceid, float* __restrict__ hout)
{
    int n = blockIdx.x;
    int o = threadIdx.x;
    float a0 = 0.f, a1 = 0.f, a2 = 0.f, a3 = 0.f;
    int beg = rowptr[n], end = rowptr[n + 1];
    for (int p = beg; p < end; ++p) {
        int d = cdst[p];
        int e = ceid[p];
        float w0 = wmin[e], w1 = wmin[EE + e], w2 = wmin[2 * EE + e], w3 = wmin[3 * EE + e];
        long b = (long)d * DH + o;
        a0 = fmaf(w0, Wh[b], a0);
        a1 = fmaf(w1, Wh[(long)NN * DH + b], a1);
        a2 = fmaf(w2, Wh[2L * NN * DH + b], a2);
        a3 = fmaf(w3, Wh[3L * NN * DH + b], a3);
    }
    float r0 = (csum[o] + a0) * invd[n];
    float r1 = (csum[DH + o] + a1) * invd[NN + n];
    float r2 = (csum[2 * DH + o] + a2) * invd[2 * NN + n];
    float r3 = (csum[3 * DH + o] + a3) * invd[3 * NN + n];
    r0 = r0 > 0.f ? r0 : expm1f(r0);
    r1 = r1 > 0.f ? r1 : expm1f(r1);
    r2 = r2 > 0.f ? r2 : expm1f(r2);
    r3 = r3 > 0.f ? r3 : expm1f(r3);
    long rb = (long)n * DCAT + o;
    hout[rb] = r0;
    hout[rb + DH] = r1;
    hout[rb + 2 * DH] = r2;
    hout[rb + 3 * DH] = r3;
}

// ------------------------------------------------------------------
// Pooling + classifier
// ------------------------------------------------------------------
__global__ void pool_score_kernel(const float* __restrict__ h3, const float* __restrict__ pw,
                                  const float* __restrict__ pb, float* __restrict__ ps)
{
    int wave = threadIdx.x >> 6, lane = threadIdx.x & 63;
    int n = blockIdx.x * 4 + wave;
    const float* row = h3 + (long)n * DCAT;
    float s = 0.f;
    for (int i = lane; i < DCAT; i += 64) s = fmaf(row[i], pw[i], s);
#pragma unroll
    for (int off = 32; off; off >>= 1) s += __shfl_down(s, off);
    if (lane == 0) ps[n] = s + pb[0];
}

__global__ void softmax_n_kernel(const float* __restrict__ s, float* __restrict__ aw)
{
    __shared__ float red[16];
    __shared__ float MM, SS;
    int t = threadIdx.x;
    float m = -1e30f;
    for (int i = t; i < NN; i += 1024) m = fmaxf(m, s[i]);
#pragma unroll
    for (int off = 32; off; off >>= 1) m = fmaxf(m, __shfl_down(m, off));
    if ((t & 63) == 0) red[t >> 6] = m;
    __syncthreads();
    if (t == 0) {
        float v = red[0];
        for (int i = 1; i < 16; ++i) v = fmaxf(v, red[i]);
        MM = v;
    }
    __syncthreads();
    float sum = 0.f;
    for (int i = t; i < NN; i += 1024) sum += expf(s[i] - MM);
#pragma unroll
    for (int off = 32; off; off >>= 1) sum += __shfl_down(sum, off);
    __syncthreads();
    if ((t & 63) == 0) red[t >> 6] = sum;
    __syncthreads();
    if (t == 0) {
        float v = 0.f;
        for (int i = 0; i < 16; ++i) v += red[i];
        SS = v;
    }
    __syncthreads();
    for (int i = t; i < NN; i += 1024) aw[i] = expf(s[i] - MM) / SS;
}

__global__ void emb_kernel(const float* __restrict__ h3, const float* __restrict__ aw,
                           float* __restrict__ emb)
{
    int o = blockIdx.x * 256 + threadIdx.x;
    int n0 = blockIdx.y * 256;
    float s = 0.f;
    for (int n = n0; n < n0 + 256; ++n) s = fmaf(aw[n], h3[(long)n * DCAT + o], s);
    atomicAdd(&emb[o], s);
}

__global__ void classifier_kernel(const float* __restrict__ emb, const float* __restrict__ c1w,
                                  const float* __restrict__ c1b, const float* __restrict__ c2w,
                                  const float* __restrict__ c2b, float* __restrict__ out)
{
    __shared__ float z[DH];
    __shared__ float lg[8];
    int t = threadIdx.x;
    float acc = c1b[t];
    for (int i = 0; i < DCAT; ++i) acc = fmaf(emb[i], c1w[(long)i * DH + t], acc);
    z[t] = acc > 0.f ? acc : 0.f;
    __syncthreads();
    if (t < 7) {
        float l = c2b[t];
        for (int i = 0; i < DH; ++i) l = fmaf(z[i], c2w[i * 7 + t], l);
        lg[t] = l;
    }
    __syncthreads();
    if (t == 0) {
        float m = lg[0];
        for (int i = 1; i < 7; ++i) m = fmaxf(m, lg[i]);
        float sm = 0.f, ex[7];
        for (int i = 0; i < 7; ++i) { ex[i] = expf(lg[i] - m); sm += ex[i]; }
        for (int i = 0; i < 7; ++i) out[i] = ex[i] / sm;
    }
}

__global__ void natt_kernel(const float* __restrict__ imp, const float* __restrict__ Ctot,
                            float* __restrict__ out)
{
    int m = blockIdx.x * 256 + threadIdx.x;
    out[7 + m] = (imp[m] + Ctot[0]) * (1.0f / 12.0f);
}

// ------------------------------------------------------------------
extern "C" void kernel_launch(void* const* d_in, const int* in_sizes, int n_in,
                              void* d_out, int out_size, void* d_ws, size_t ws_size,
                              hipStream_t stream)
{
    const float* x   = (const float*)d_in[0];
    const int*   ei  = (const int*)d_in[1];
    const float* Wp  = (const float*)d_in[2];
    const float* bp  = (const float*)d_in[3];
    const float* W[3]  = {(const float*)d_in[4], (const float*)d_in[6], (const float*)d_in[8]};
    const float* av[3] = {(const float*)d_in[5], (const float*)d_in[7], (const float*)d_in[9]};
    const float* pw  = (const float*)d_in[10];
    const float* pb  = (const float*)d_in[11];
    const float* c1w = (const float*)d_in[12];
    const float* c1b = (const float*)d_in[13];
    const float* c2w = (const float*)d_in[14];
    const float* c2b = (const float*)d_in[15];
    float* out = (float*)d_out;
    (void)in_sizes; (void)n_in; (void)out_size; (void)ws_size;

    char* base = (char*)d_ws;
    size_t off = 0;
    auto alloc = [&](size_t bytes) -> void* {
        void* p = base + off;
        off = (off + bytes + 255) & ~(size_t)255;
        return p;
    };
    float* h_a   = (float*)alloc((size_t)NN * DCAT * 4);
    float* h_b   = (float*)alloc((size_t)NN * DCAT * 4);
    float* Wh    = (float*)alloc((size_t)HH * NN * DH * 4);
    float* wmin  = (float*)alloc((size_t)HH * EE * 4);
    float* es    = (float*)alloc(HH * NN * 4);
    float* ed    = (float*)alloc(HH * NN * 4);
    float* dacc  = (float*)alloc(HH * NN * 4);
    float* invd  = (float*)alloc(HH * NN * 4);
    float* csum  = (float*)alloc(HH * DH * 4);
    float* imp   = (float*)alloc(NN * 4);
    float* Ctot  = (float*)alloc(256);
    int*   counts = (int*)alloc(NN * 4);
    int*   rowptr = (int*)alloc((NN + 1) * 4);
    int*   cursor = (int*)alloc(NN * 4);
    int*   cdst   = (int*)alloc(EE * 4);
    int*   ceid   = (int*)alloc(EE * 4);
    float* ps    = (float*)alloc(NN * 4);
    float* paw   = (float*)alloc(NN * 4);
    float* emb   = (float*)alloc(DCAT * 4);

    const int* srcp = ei;
    const int* dstp = ei + EE;

    // zero accumulators (re-init every call; ws is not re-poisoned between replays)
    hipMemsetAsync(imp, 0, NN * 4, stream);
    hipMemsetAsync(Ctot, 0, 256, stream);
    hipMemsetAsync(counts, 0, NN * 4, stream);
    hipMemsetAsync(emb, 0, DCAT * 4, stream);

    // CSR build (deterministic recompute each call)
    count_kernel<<<EE / 256, 256, 0, stream>>>(srcp, counts);
    scan_kernel<<<1, 1024, 0, stream>>>(counts, rowptr);
    copy_int_kernel<<<NN / 256, 256, 0, stream>>>(rowptr, cursor, NN);
    fill_kernel<<<EE / 256, 256, 0, stream>>>(srcp, dstp, cursor, cdst, ceid);

    // input projection: h_a[N][256] = relu(x @ Wp + bp)
    gemm_kernel<<<dim3(NN / 64, DH / 64, 1), 256, 0, stream>>>(
        x, DIN, Wp, 0, DH, h_a, 0, DH, DIN, bp, 1);

    float* cur = h_a;  int lin = DH;
    float* nxt = h_b;
    for (int layer = 0; layer < 3; ++layer) {
        int K = (layer == 0) ? DH : DCAT;
        lin = K;
        // Wh[h][N][256] = cur @ W[layer][h]
        gemm_kernel<<<dim3(NN / 64, DH / 64, HH), 256, 0, stream>>>(
            cur, lin, W[layer], (long)K * DH, DH, Wh, (long)NN * DH, DH, K, nullptr, 0);
        attvec_kernel<<<HH * NN / 4, 256, 0, stream>>>(Wh, av[layer], es, ed);
        hipMemsetAsync(dacc, 0, HH * NN * 4, stream);
        hipMemsetAsync(csum, 0, HH * DH * 4, stream);
        edge_kernel<<<EE / 256, 256, 0, stream>>>(srcp, dstp, es, ed, wmin, dacc);
        denom_kernel<<<HH * NN / 256, 256, 0, stream>>>(dacc, invd);
        reduce_add_kernel<<<16, 256, 0, stream>>>(invd, HH * NN, Ctot);
        imp_kernel<<<EE / 256, 256, 0, stream>>>(srcp, dstp, wmin, invd, imp);
        colsum_kernel<<<HH * (NN / 256), 256, 0, stream>>>(Wh, csum);
        agg_kernel<<<NN, 256, 0, stream>>>(Wh, wmin, invd, csum, rowptr, cdst, ceid, nxt);
        float* t = cur; cur = nxt; nxt = t;
    }
    // cur == final h3 [N][1024]
    pool_score_kernel<<<NN / 4, 256, 0, stream>>>(cur, pw, pb, ps);
    softmax_n_kernel<<<1, 1024, 0, stream>>>(ps, paw);
    emb_kernel<<<dim3(DCAT / 256, NN / 256), 256, 0, stream>>>(cur, paw, emb);
    classifier_kernel<<<1, 256, 0, stream>>>(emb, c1w, c1b, c2w, c2b, out);
    natt_kernel<<<NN / 256, 256, 0, stream>>>(imp, Ctot, out);
}

// Round 2
// 692.813 us; speedup vs baseline: 1.5958x; 1.5958x over previous
//
#include <hip/hip_runtime.h>
#include <hip/hip_bf16.h>
#include <math.h>

#define NN   4096
#define EE   131072
#define HH   4
#define DIN  128
#define DH   256
#define DCAT 1024   /* HH*DH */
#define ALPHA_LR 0.2f

typedef __attribute__((ext_vector_type(8))) short  short8;
typedef __attribute__((ext_vector_type(4))) short  s16x4;
typedef __attribute__((ext_vector_type(4))) float  f32x4;

__device__ __forceinline__ unsigned short f2bf(float f) {
    union { float f; unsigned u; } v; v.f = f;
    unsigned r = v.u + 0x7fffu + ((v.u >> 16) & 1u);
    return (unsigned short)(r >> 16);
}
__device__ __forceinline__ float bf2f(unsigned short us) {
    union { unsigned u; float f; } v; v.u = ((unsigned)us) << 16;
    return v.f;
}

// ------------------------------------------------------------------
// cast fp32 -> bf16, 4 elems/thread
// ------------------------------------------------------------------
__global__ void cast_kernel(const float* __restrict__ in, unsigned short* __restrict__ out, int n4)
{
    int i = blockIdx.x * 256 + threadIdx.x;
    if (i < n4) {
        f32x4 v = *(const f32x4*)(in + (size_t)i * 4);
        s16x4 o;
        o[0] = (short)f2bf(v[0]); o[1] = (short)f2bf(v[1]);
        o[2] = (short)f2bf(v[2]); o[3] = (short)f2bf(v[3]);
        *(s16x4*)(out + (size_t)i * 4) = o;
    }
}

// ------------------------------------------------------------------
// transpose+cast: W[h][K][256] fp32 -> BT[h*256+o][K] bf16
// grid (K/32, 8, H), block 256 (32x8)
// ------------------------------------------------------------------
__global__ void transpose_cast_kernel(const float* __restrict__ W, unsigned short* __restrict__ BT, int K)
{
    __shared__ float tile[32][33];
    int h = blockIdx.z;
    int k0 = blockIdx.x * 32, o0 = blockIdx.y * 32;
    int tx = threadIdx.x & 31, ty = threadIdx.x >> 5;
    const float* Ws = W + (size_t)h * K * 256;
#pragma unroll
    for (int i = 0; i < 32; i += 8)
        tile[ty + i][tx] = Ws[(size_t)(k0 + ty + i) * 256 + o0 + tx];
    __syncthreads();
#pragma unroll
    for (int i = 0; i < 32; i += 8)
        BT[(size_t)(h * 256 + o0 + ty + i) * K + k0 + tx] = f2bf(tile[tx][ty + i]);
}

// ------------------------------------------------------------------
// bf16 MFMA GEMM: C[M][ldc] = act(A[M][K] @ BT[N][K]^T + bias)
// 128x128 tile, 256 threads (4 waves, 2x2), 16x16x32 MFMA,
// double-buffered LDS staged via global_load_lds width=16.
// ------------------------------------------------------------------
__global__ __launch_bounds__(256)
void mfma_gemm_kernel(const unsigned short* __restrict__ A,
                      const unsigned short* __restrict__ BT,
                      int K,
                      unsigned short* __restrict__ Cb,  // bf16 out (or null)
                      float* __restrict__ Cf,           // fp32 out (or null)
                      int ldc,
                      const float* __restrict__ bias, int relu_act)
{
    __shared__ __align__(16) unsigned short sA[2][128 * 32];
    __shared__ __align__(16) unsigned short sB[2][128 * 32];

    const int tid = threadIdx.x;
    const int w = tid >> 6, l = tid & 63;
    const int wr = w >> 1, wc = w & 1;
    const int row0 = blockIdx.x * 128, col0 = blockIdx.y * 128;
    const int lrow = l >> 2;            // staging: row within 16-row chunk
    const int lce  = (l & 3) * 8;       // staging: elem offset (8 bf16 = 16B)
    const int lr = l & 15, lg = l >> 4; // fragment lane decomposition

    f32x4 acc[4][4];
#pragma unroll
    for (int m = 0; m < 4; ++m)
#pragma unroll
        for (int n = 0; n < 4; ++n)
            acc[m][n] = (f32x4){0.f, 0.f, 0.f, 0.f};

#define STAGE(buf, k0)                                                          \
    {                                                                           \
        _Pragma("unroll")                                                       \
        for (int p = 0; p < 2; ++p) {                                           \
            int chunk = w * 2 + p;                                              \
            int r = chunk * 16 + lrow;                                          \
            const unsigned short* ga = A  + (size_t)(row0 + r) * K + (k0) + lce;\
            const unsigned short* gb = BT + (size_t)(col0 + r) * K + (k0) + lce;\
            __builtin_amdgcn_global_load_lds(                                   \
                (const __attribute__((address_space(1))) unsigned int*)ga,      \
                (__attribute__((address_space(3))) unsigned int*)(&sA[buf][chunk * 512]), \
                16, 0, 0);                                                      \
            __builtin_amdgcn_global_load_lds(                                   \
                (const __attribute__((address_space(1))) unsigned int*)gb,      \
                (__attribute__((address_space(3))) unsigned int*)(&sB[buf][chunk * 512]), \
                16, 0, 0);                                                      \
        }                                                                       \
    }

#define COMPUTE(buf)                                                            \
    {                                                                           \
        short8 af[4], bfr[4];                                                   \
        _Pragma("unroll")                                                       \
        for (int m = 0; m < 4; ++m) {                                           \
            int r = wr * 64 + m * 16 + lr;                                      \
            af[m] = *(const short8*)(&sA[buf][r * 32 + lg * 8]);                \
        }                                                                       \
        _Pragma("unroll")                                                       \
        for (int n = 0; n < 4; ++n) {                                           \
            int r = wc * 64 + n * 16 + lr;                                      \
            bfr[n] = *(const short8*)(&sB[buf][r * 32 + lg * 8]);               \
        }                                                                       \
        _Pragma("unroll")                                                       \
        for (int m = 0; m < 4; ++m)                                             \
            _Pragma("unroll")                                                   \
            for (int n = 0; n < 4; ++n)                                         \
                acc[m][n] = __builtin_amdgcn_mfma_f32_16x16x32_bf16(            \
                    af[m], bfr[n], acc[m][n], 0, 0, 0);                         \
    }

    STAGE(0, 0);
    __syncthreads();
    int nt = K >> 5, cur = 0;
    for (int t = 0; t < nt - 1; ++t) {
        STAGE(cur ^ 1, (t + 1) * 32);
        COMPUTE(cur);
        __syncthreads();
        cur ^= 1;
    }
    COMPUTE(cur);
#undef STAGE
#undef COMPUTE

    // epilogue: C[row=(lg*4+r)][col=lr] per fragment (verified C/D map)
#pragma unroll
    for (int m = 0; m < 4; ++m) {
        int rbase = row0 + wr * 64 + m * 16 + lg * 4;
#pragma unroll
        for (int n = 0; n < 4; ++n) {
            int c = col0 + wc * 64 + n * 16 + lr;
            float bv = bias ? bias[c] : 0.f;
#pragma unroll
            for (int r = 0; r < 4; ++r) {
                float v = acc[m][n][r] + bv;
                if (relu_act) v = fmaxf(v, 0.f);
                size_t idx = (size_t)(rbase + r) * ldc + c;
                if (Cb) Cb[idx] = f2bf(v);
                if (Cf) Cf[idx] = v;
            }
        }
    }
}

// ------------------------------------------------------------------
// e_src / e_dst row dots. Wh layout [n][h*256+o] bf16.
// One wave per (h,n); 4 waves/block.
// ------------------------------------------------------------------
__global__ void attvec_kernel(const unsigned short* __restrict__ Whb, const float* __restrict__ a,
                              float* __restrict__ es, float* __restrict__ ed)
{
    int wave = threadIdx.x >> 6, lane = threadIdx.x & 63;
    int idx = blockIdx.x * 4 + wave;   // idx = h*NN + n
    int h = idx >> 12, n = idx & 4095;
    const unsigned short* row = Whb + (size_t)n * DCAT + h * DH + lane * 4;
    const float* ah = a + h * 2 * DH + lane * 4;
    s16x4 wv = *(const s16x4*)row;
    f32x4 a1 = *(const f32x4*)ah;
    f32x4 a2 = *(const f32x4*)(ah + DH);
    float s1 = 0.f, s2 = 0.f;
#pragma unroll
    for (int j = 0; j < 4; ++j) {
        float wf = bf2f((unsigned short)wv[j]);
        s1 = fmaf(a1[j], wf, s1);
        s2 = fmaf(a2[j], wf, s2);
    }
#pragma unroll
    for (int off = 32; off; off >>= 1) {
        s1 += __shfl_down(s1, off);
        s2 += __shfl_down(s2, off);
    }
    if (lane == 0) { es[idx] = s1; ed[idx] = s2; }
}

// ------------------------------------------------------------------
// Per-edge weights + denominators
// ------------------------------------------------------------------
__global__ void edge_kernel(const int* __restrict__ src, const int* __restrict__ dst,
                            const float* __restrict__ es, const float* __restrict__ ed,
                            float* __restrict__ wmin, float* __restrict__ dacc)
{
    int e = blockIdx.x * 256 + threadIdx.x;
    int s = src[e], d = dst[e];
#pragma unroll
    for (int h = 0; h < HH; ++h) {
        float v = es[h * NN + s] + ed[h * NN + d];
        v = v > 0.f ? v : ALPHA_LR * v;
        float w = expm1f(v);
        wmin[h * EE + e] = w;
        atomicAdd(&dacc[h * NN + s], w);
    }
}

__global__ void denom_kernel(const float* __restrict__ dacc, float* __restrict__ invd)
{
    int i = blockIdx.x * 256 + threadIdx.x;
    invd[i] = 1.f / ((float)NN + dacc[i]);
}

__global__ void reduce_add_kernel(const float* __restrict__ v, int n, float* __restrict__ out)
{
    float s = 0.f;
    for (int i = blockIdx.x * blockDim.x + threadIdx.x; i < n; i += gridDim.x * blockDim.x)
        s += v[i];
#pragma unroll
    for (int off = 32; off; off >>= 1) s += __shfl_down(s, off);
    __shared__ float red[4];
    if ((threadIdx.x & 63) == 0) red[threadIdx.x >> 6] = s;
    __syncthreads();
    if (threadIdx.x == 0) atomicAdd(out, red[0] + red[1] + red[2] + red[3]);
}

__global__ void imp_kernel(const int* __restrict__ src, const int* __restrict__ dst,
                           const float* __restrict__ wmin, const float* __restrict__ invd,
                           float* __restrict__ imp)
{
    int e = blockIdx.x * 256 + threadIdx.x;
    int s = src[e], d = dst[e];
    float t = wmin[e] * invd[s]
            + wmin[EE + e] * invd[NN + s]
            + wmin[2 * EE + e] * invd[2 * NN + s]
            + wmin[3 * EE + e] * invd[3 * NN + s];
    atomicAdd(&imp[d], t);
}

// column sums of Wh per head (Wh [n][h*256+o] bf16)
__global__ void colsum_kernel(const unsigned short* __restrict__ Whb, float* __restrict__ csum)
{
    int h = blockIdx.x >> 5;        // grid = H*32
    int chunk = blockIdx.x & 31;    // 128 rows each
    int o = threadIdx.x;
    float s = 0.f;
    for (int n = chunk * 128; n < chunk * 128 + 128; ++n)
        s += bf2f(Whb[(size_t)n * DCAT + h * DH + o]);
    atomicAdd(&csum[h * DH + o], s);
}

// ------------------------------------------------------------------
// CSR build
// ------------------------------------------------------------------
__global__ void count_kernel(const int* __restrict__ src, int* __restrict__ counts)
{
    int e = blockIdx.x * 256 + threadIdx.x;
    atomicAdd(&counts[src[e]], 1);
}

__global__ void scan_kernel(const int* __restrict__ counts, int* __restrict__ rowptr)
{
    __shared__ int lsum[1024];
    int t = threadIdx.x;
    int base = t * 4;
    int c0 = counts[base], c1 = counts[base + 1], c2 = counts[base + 2], c3 = counts[base + 3];
    int s = c0 + c1 + c2 + c3;
    lsum[t] = s;
    __syncthreads();
    for (int off = 1; off < 1024; off <<= 1) {
        int v = (t >= off) ? lsum[t - off] : 0;
        __syncthreads();
        lsum[t] += v;
        __syncthreads();
    }
    int excl = lsum[t] - s;
    rowptr[base] = excl;
    rowptr[base + 1] = excl + c0;
    rowptr[base + 2] = excl + c0 + c1;
    rowptr[base + 3] = excl + c0 + c1 + c2;
    if (t == 1023) rowptr[NN] = lsum[1023];
}

__global__ void copy_int_kernel(const int* __restrict__ a, int* __restrict__ b, int n)
{
    int i = blockIdx.x * 256 + threadIdx.x;
    if (i < n) b[i] = a[i];
}

__global__ void fill_kernel(const int* __restrict__ src, const int* __restrict__ dst,
                            int* __restrict__ cursor, int* __restrict__ cdst,
                            int* __restrict__ ceid)
{
    int e = blockIdx.x * 256 + threadIdx.x;
    int s = src[e];
    int pos = atomicAdd(&cursor[s], 1);
    cdst[pos] = dst[e];
    ceid[pos] = e;
}

// ------------------------------------------------------------------
// Aggregation: block per node n, thread per within-head output o.
// Wh bf16 [d][h*256+o]; writes bf16 h (next GEMM) + fp32 h (pooling).
// ------------------------------------------------------------------
__global__ void agg_kernel(const unsigned short* __restrict__ Whb, const float* __restrict__ wmin,
                           const float* __restrict__ invd, const float* __restrict__ csum,
                           const int* __restrict__ rowptr, const int* __restrict__ cdst,
                           const int* __restrict__ ceid,
                           unsigned short* __restrict__ hb_out, float* __restrict__ hf_out)
{
    int n = blockIdx.x;
    int o = threadIdx.x;
    float a0 = 0.f, a1 = 0.f, a2 = 0.f, a3 = 0.f;
    int beg = rowptr[n], end = rowptr[n + 1];
    for (int p = beg; p < end; ++p) {
        int d = cdst[p];
        int e = ceid[p];
        const unsigned short* wrow = Whb + (size_t)d * DCAT + o;
        a0 = fmaf(wmin[e],          bf2f(wrow[0]),       a0);
        a1 = fmaf(wmin[EE + e],     bf2f(wrow[DH]),      a1);
        a2 = fmaf(wmin[2 * EE + e], bf2f(wrow[2 * DH]),  a2);
        a3 = fmaf(wmin[3 * EE + e], bf2f(wrow[3 * DH]),  a3);
    }
    float r0 = (csum[o] + a0) * invd[n];
    float r1 = (csum[DH + o] + a1) * invd[NN + n];
    float r2 = (csum[2 * DH + o] + a2) * invd[2 * NN + n];
    float r3 = (csum[3 * DH + o] + a3) * invd[3 * NN + n];
    r0 = r0 > 0.f ? r0 : expm1f(r0);
    r1 = r1 > 0.f ? r1 : expm1f(r1);
    r2 = r2 > 0.f ? r2 : expm1f(r2);
    r3 = r3 > 0.f ? r3 : expm1f(r3);
    size_t rb = (size_t)n * DCAT + o;
    hb_out[rb] = f2bf(r0);           hf_out[rb] = r0;
    hb_out[rb + DH] = f2bf(r1);      hf_out[rb + DH] = r1;
    hb_out[rb + 2 * DH] = f2bf(r2);  hf_out[rb + 2 * DH] = r2;
    hb_out[rb + 3 * DH] = f2bf(r3);  hf_out[rb + 3 * DH] = r3;
}

// ------------------------------------------------------------------
// Pooling + classifier (fp32 h3)
// ------------------------------------------------------------------
__global__ void pool_score_kernel(const float* __restrict__ h3, const float* __restrict__ pw,
                                  const float* __restrict__ pb, float* __restrict__ ps)
{
    int wave = threadIdx.x >> 6, lane = threadIdx.x & 63;
    int n = blockIdx.x * 4 + wave;
    const float* row = h3 + (size_t)n * DCAT;
    float s = 0.f;
    for (int i = lane; i < DCAT; i += 64) s = fmaf(row[i], pw[i], s);
#pragma unroll
    for (int off = 32; off; off >>= 1) s += __shfl_down(s, off);
    if (lane == 0) ps[n] = s + pb[0];
}

__global__ void softmax_n_kernel(const float* __restrict__ s, float* __restrict__ aw)
{
    __shared__ float red[16];
    __shared__ float MM, SS;
    int t = threadIdx.x;
    float m = -1e30f;
    for (int i = t; i < NN; i += 1024) m = fmaxf(m, s[i]);
#pragma unroll
    for (int off = 32; off; off >>= 1) m = fmaxf(m, __shfl_down(m, off));
    if ((t & 63) == 0) red[t >> 6] = m;
    __syncthreads();
    if (t == 0) {
        float v = red[0];
        for (int i = 1; i < 16; ++i) v = fmaxf(v, red[i]);
        MM = v;
    }
    __syncthreads();
    float sum = 0.f;
    for (int i = t; i < NN; i += 1024) sum += expf(s[i] - MM);
#pragma unroll
    for (int off = 32; off; off >>= 1) sum += __shfl_down(sum, off);
    __syncthreads();
    if ((t & 63) == 0) red[t >> 6] = sum;
    __syncthreads();
    if (t == 0) {
        float v = 0.f;
        for (int i = 0; i < 16; ++i) v += red[i];
        SS = v;
    }
    __syncthreads();
    for (int i = t; i < NN; i += 1024) aw[i] = expf(s[i] - MM) / SS;
}

__global__ void emb_kernel(const float* __restrict__ h3, const float* __restrict__ aw,
                           float* __restrict__ emb)
{
    int o = blockIdx.x * 256 + threadIdx.x;
    int n0 = blockIdx.y * 256;
    float s = 0.f;
    for (int n = n0; n < n0 + 256; ++n) s = fmaf(aw[n], h3[(size_t)n * DCAT + o], s);
    atomicAdd(&emb[o], s);
}

__global__ void classifier_kernel(const float* __restrict__ emb, const float* __restrict__ c1w,
                                  const float* __restrict__ c1b, const float* __restrict__ c2w,
                                  const float* __restrict__ c2b, float* __restrict__ out)
{
    __shared__ float z[DH];
    __shared__ float lg[8];
    int t = threadIdx.x;
    float acc = c1b[t];
    for (int i = 0; i < DCAT; ++i) acc = fmaf(emb[i], c1w[(size_t)i * DH + t], acc);
    z[t] = acc > 0.f ? acc : 0.f;
    __syncthreads();
    if (t < 7) {
        float l = c2b[t];
        for (int i = 0; i < DH; ++i) l = fmaf(z[i], c2w[i * 7 + t], l);
        lg[t] = l;
    }
    __syncthreads();
    if (t == 0) {
        float m = lg[0];
        for (int i = 1; i < 7; ++i) m = fmaxf(m, lg[i]);
        float sm = 0.f, ex[7];
        for (int i = 0; i < 7; ++i) { ex[i] = expf(lg[i] - m); sm += ex[i]; }
        for (int i = 0; i < 7; ++i) out[i] = ex[i] / sm;
    }
}

__global__ void natt_kernel(const float* __restrict__ imp, const float* __restrict__ Ctot,
                            float* __restrict__ out)
{
    int m = blockIdx.x * 256 + threadIdx.x;
    out[7 + m] = (imp[m] + Ctot[0]) * (1.0f / 12.0f);
}

// ------------------------------------------------------------------
extern "C" void kernel_launch(void* const* d_in, const int* in_sizes, int n_in,
                              void* d_out, int out_size, void* d_ws, size_t ws_size,
                              hipStream_t stream)
{
    const float* x   = (const float*)d_in[0];
    const int*   ei  = (const int*)d_in[1];
    const float* Wp  = (const float*)d_in[2];
    const float* bp  = (const float*)d_in[3];
    const float* W[3]  = {(const float*)d_in[4], (const float*)d_in[6], (const float*)d_in[8]};
    const float* av[3] = {(const float*)d_in[5], (const float*)d_in[7], (const float*)d_in[9]};
    const float* pw  = (const float*)d_in[10];
    const float* pb  = (const float*)d_in[11];
    const float* c1w = (const float*)d_in[12];
    const float* c1b = (const float*)d_in[13];
    const float* c2w = (const float*)d_in[14];
    const float* c2b = (const float*)d_in[15];
    float* out = (float*)d_out;
    (void)in_sizes; (void)n_in; (void)out_size; (void)ws_size;

    char* base = (char*)d_ws;
    size_t off = 0;
    auto alloc = [&](size_t bytes) -> void* {
        void* p = base + off;
        off = (off + bytes + 255) & ~(size_t)255;
        return p;
    };
    unsigned short* xb   = (unsigned short*)alloc((size_t)NN * DIN * 2);
    unsigned short* BTp  = (unsigned short*)alloc((size_t)DH * DIN * 2);
    unsigned short* BT0  = (unsigned short*)alloc((size_t)DCAT * DH * 2);
    unsigned short* BT1  = (unsigned short*)alloc((size_t)DCAT * DCAT * 2);
    unsigned short* BT2  = (unsigned short*)alloc((size_t)DCAT * DCAT * 2);
    unsigned short* Whb  = (unsigned short*)alloc((size_t)NN * DCAT * 2);
    unsigned short* hb0  = (unsigned short*)alloc((size_t)NN * DCAT * 2);
    unsigned short* hb1  = (unsigned short*)alloc((size_t)NN * DCAT * 2);
    float* hf    = (float*)alloc((size_t)NN * DCAT * 4);
    float* wmin  = (float*)alloc((size_t)HH * EE * 4);
    float* es    = (float*)alloc(HH * NN * 4);
    float* ed    = (float*)alloc(HH * NN * 4);
    float* dacc  = (float*)alloc(HH * NN * 4);
    float* invd  = (float*)alloc(HH * NN * 4);
    float* csum  = (float*)alloc(HH * DH * 4);
    float* imp   = (float*)alloc(NN * 4);
    float* Ctot  = (float*)alloc(256);
    int*   counts = (int*)alloc(NN * 4);
    int*   rowptr = (int*)alloc((NN + 1) * 4);
    int*   cursor = (int*)alloc(NN * 4);
    int*   cdst   = (int*)alloc(EE * 4);
    int*   ceid   = (int*)alloc(EE * 4);
    float* ps    = (float*)alloc(NN * 4);
    float* paw   = (float*)alloc(NN * 4);
    float* emb   = (float*)alloc(DCAT * 4);

    const int* srcp = ei;
    const int* dstp = ei + EE;

    hipMemsetAsync(imp, 0, NN * 4, stream);
    hipMemsetAsync(Ctot, 0, 256, stream);
    hipMemsetAsync(counts, 0, NN * 4, stream);
    hipMemsetAsync(emb, 0, DCAT * 4, stream);

    // CSR build
    count_kernel<<<EE / 256, 256, 0, stream>>>(srcp, counts);
    scan_kernel<<<1, 1024, 0, stream>>>(counts, rowptr);
    copy_int_kernel<<<NN / 256, 256, 0, stream>>>(rowptr, cursor, NN);
    fill_kernel<<<EE / 256, 256, 0, stream>>>(srcp, dstp, cursor, cdst, ceid);

    // casts / repacks
    cast_kernel<<<(NN * DIN / 4 + 255) / 256, 256, 0, stream>>>(x, xb, NN * DIN / 4);
    transpose_cast_kernel<<<dim3(DIN / 32, 8, 1), 256, 0, stream>>>(Wp, BTp, DIN);
    transpose_cast_kernel<<<dim3(DH / 32, 8, HH), 256, 0, stream>>>(W[0], BT0, DH);
    transpose_cast_kernel<<<dim3(DCAT / 32, 8, HH), 256, 0, stream>>>(W[1], BT1, DCAT);
    transpose_cast_kernel<<<dim3(DCAT / 32, 8, HH), 256, 0, stream>>>(W[2], BT2, DCAT);

    // projection: hb0[N][256] = relu(x @ Wp + bp)  (bf16 out)
    mfma_gemm_kernel<<<dim3(NN / 128, DH / 128), 256, 0, stream>>>(
        xb, BTp, DIN, hb0, nullptr, DH, bp, 1);

    unsigned short* cur = hb0;
    unsigned short* nxt = hb1;
    const unsigned short* BTl[3] = {BT0, BT1, BT2};
    for (int layer = 0; layer < 3; ++layer) {
        int K = (layer == 0) ? DH : DCAT;
        // Whb[n][h*256+o] = cur @ W[layer]  (bf16 out)
        mfma_gemm_kernel<<<dim3(NN / 128, DCAT / 128), 256, 0, stream>>>(
            cur, BTl[layer], K, Whb, nullptr, DCAT, nullptr, 0);
        attvec_kernel<<<HH * NN / 4, 256, 0, stream>>>(Whb, av[layer], es, ed);
        hipMemsetAsync(dacc, 0, HH * NN * 4, stream);
        hipMemsetAsync(csum, 0, HH * DH * 4, stream);
        edge_kernel<<<EE / 256, 256, 0, stream>>>(srcp, dstp, es, ed, wmin, dacc);
        denom_kernel<<<HH * NN / 256, 256, 0, stream>>>(dacc, invd);
        reduce_add_kernel<<<16, 256, 0, stream>>>(invd, HH * NN, Ctot);
        imp_kernel<<<EE / 256, 256, 0, stream>>>(srcp, dstp, wmin, invd, imp);
        colsum_kernel<<<HH * 32, 256, 0, stream>>>(Whb, csum);
        agg_kernel<<<NN, 256, 0, stream>>>(Whb, wmin, invd, csum, rowptr, cdst, ceid, nxt, hf);
        unsigned short* t = cur; cur = nxt; nxt = t;
    }

    // pooling + classifier on fp32 h3 (hf holds final layer)
    pool_score_kernel<<<NN / 4, 256, 0, stream>>>(hf, pw, pb, ps);
    softmax_n_kernel<<<1, 1024, 0, stream>>>(ps, paw);
    emb_kernel<<<dim3(DCAT / 256, NN / 256), 256, 0, stream>>>(hf, paw, emb);
    classifier_kernel<<<1, 256, 0, stream>>>(emb, c1w, c1b, c2w, c2b, out);
    natt_kernel<<<NN / 256, 256, 0, stream>>>(imp, Ctot, out);
}

// Round 3
// 496.955 us; speedup vs baseline: 2.2248x; 1.3941x over previous
//
#include <hip/hip_runtime.h>
#include <hip/hip_bf16.h>
#include <math.h>

#define NN   4096
#define EE   131072
#define HH   4
#define DIN  128
#define DH   256
#define DCAT 1024   /* HH*DH */
#define ALPHA_LR 0.2f

typedef __attribute__((ext_vector_type(8))) short  short8;
typedef __attribute__((ext_vector_type(4))) short  s16x4;
typedef __attribute__((ext_vector_type(4))) float  f32x4;

__device__ __forceinline__ unsigned short f2bf(float f) {
    union { float f; unsigned u; } v; v.f = f;
    unsigned r = v.u + 0x7fffu + ((v.u >> 16) & 1u);
    return (unsigned short)(r >> 16);
}
__device__ __forceinline__ float bf2f(unsigned short us) {
    union { unsigned u; float f; } v; v.u = ((unsigned)us) << 16;
    return v.f;
}

// ------------------------------------------------------------------
// cast fp32 -> bf16, 4 elems/thread
// ------------------------------------------------------------------
__global__ void cast_kernel(const float* __restrict__ in, unsigned short* __restrict__ out, int n4)
{
    int i = blockIdx.x * 256 + threadIdx.x;
    if (i < n4) {
        f32x4 v = *(const f32x4*)(in + (size_t)i * 4);
        s16x4 o;
        o[0] = (short)f2bf(v[0]); o[1] = (short)f2bf(v[1]);
        o[2] = (short)f2bf(v[2]); o[3] = (short)f2bf(v[3]);
        *(s16x4*)(out + (size_t)i * 4) = o;
    }
}

// ------------------------------------------------------------------
// transpose+cast: W[h][K][256] fp32 -> BT[h*256+o][K] bf16
// ------------------------------------------------------------------
__global__ void transpose_cast_kernel(const float* __restrict__ W, unsigned short* __restrict__ BT, int K)
{
    __shared__ float tile[32][33];
    int h = blockIdx.z;
    int k0 = blockIdx.x * 32, o0 = blockIdx.y * 32;
    int tx = threadIdx.x & 31, ty = threadIdx.x >> 5;
    const float* Ws = W + (size_t)h * K * 256;
#pragma unroll
    for (int i = 0; i < 32; i += 8)
        tile[ty + i][tx] = Ws[(size_t)(k0 + ty + i) * 256 + o0 + tx];
    __syncthreads();
#pragma unroll
    for (int i = 0; i < 32; i += 8)
        BT[(size_t)(h * 256 + o0 + ty + i) * K + k0 + tx] = f2bf(tile[tx][ty + i]);
}

// ------------------------------------------------------------------
// bf16 MFMA GEMM: C = act(A[M][K] @ BT[N][K]^T + bias), 128x128 tile.
// ------------------------------------------------------------------
__global__ __launch_bounds__(256)
void mfma_gemm_kernel(const unsigned short* __restrict__ A,
                      const unsigned short* __restrict__ BT,
                      int K,
                      unsigned short* __restrict__ Cb,
                      float* __restrict__ Cf,
                      int ldc,
                      const float* __restrict__ bias, int relu_act)
{
    __shared__ __align__(16) unsigned short sA[2][128 * 32];
    __shared__ __align__(16) unsigned short sB[2][128 * 32];

    const int tid = threadIdx.x;
    const int w = tid >> 6, l = tid & 63;
    const int wr = w >> 1, wc = w & 1;
    const int row0 = blockIdx.x * 128, col0 = blockIdx.y * 128;
    const int lrow = l >> 2;
    const int lce  = (l & 3) * 8;
    const int lr = l & 15, lg = l >> 4;

    f32x4 acc[4][4];
#pragma unroll
    for (int m = 0; m < 4; ++m)
#pragma unroll
        for (int n = 0; n < 4; ++n)
            acc[m][n] = (f32x4){0.f, 0.f, 0.f, 0.f};

#define STAGE(buf, k0)                                                          \
    {                                                                           \
        _Pragma("unroll")                                                       \
        for (int p = 0; p < 2; ++p) {                                           \
            int chunk = w * 2 + p;                                              \
            int r = chunk * 16 + lrow;                                          \
            const unsigned short* ga = A  + (size_t)(row0 + r) * K + (k0) + lce;\
            const unsigned short* gb = BT + (size_t)(col0 + r) * K + (k0) + lce;\
            __builtin_amdgcn_global_load_lds(                                   \
                (const __attribute__((address_space(1))) unsigned int*)ga,      \
                (__attribute__((address_space(3))) unsigned int*)(&sA[buf][chunk * 512]), \
                16, 0, 0);                                                      \
            __builtin_amdgcn_global_load_lds(                                   \
                (const __attribute__((address_space(1))) unsigned int*)gb,      \
                (__attribute__((address_space(3))) unsigned int*)(&sB[buf][chunk * 512]), \
                16, 0, 0);                                                      \
        }                                                                       \
    }

#define COMPUTE(buf)                                                            \
    {                                                                           \
        short8 af[4], bfr[4];                                                   \
        _Pragma("unroll")                                                       \
        for (int m = 0; m < 4; ++m) {                                           \
            int r = wr * 64 + m * 16 + lr;                                      \
            af[m] = *(const short8*)(&sA[buf][r * 32 + lg * 8]);                \
        }                                                                       \
        _Pragma("unroll")                                                       \
        for (int n = 0; n < 4; ++n) {                                           \
            int r = wc * 64 + n * 16 + lr;                                      \
            bfr[n] = *(const short8*)(&sB[buf][r * 32 + lg * 8]);               \
        }                                                                       \
        _Pragma("unroll")                                                       \
        for (int m = 0; m < 4; ++m)                                             \
            _Pragma("unroll")                                                   \
            for (int n = 0; n < 4; ++n)                                         \
                acc[m][n] = __builtin_amdgcn_mfma_f32_16x16x32_bf16(            \
                    af[m], bfr[n], acc[m][n], 0, 0, 0);                         \
    }

    STAGE(0, 0);
    __syncthreads();
    int nt = K >> 5, cur = 0;
    for (int t = 0; t < nt - 1; ++t) {
        STAGE(cur ^ 1, (t + 1) * 32);
        COMPUTE(cur);
        __syncthreads();
        cur ^= 1;
    }
    COMPUTE(cur);
#undef STAGE
#undef COMPUTE

#pragma unroll
    for (int m = 0; m < 4; ++m) {
        int rbase = row0 + wr * 64 + m * 16 + lg * 4;
#pragma unroll
        for (int n = 0; n < 4; ++n) {
            int c = col0 + wc * 64 + n * 16 + lr;
            float bv = bias ? bias[c] : 0.f;
#pragma unroll
            for (int r = 0; r < 4; ++r) {
                float v = acc[m][n][r] + bv;
                if (relu_act) v = fmaxf(v, 0.f);
                size_t idx = (size_t)(rbase + r) * ldc + c;
                if (Cb) Cb[idx] = f2bf(v);
                if (Cf) Cf[idx] = v;
            }
        }
    }
}

// ------------------------------------------------------------------
// e_src / e_dst row dots. Wh layout [n][h*256+o] bf16.
// ------------------------------------------------------------------
__global__ void attvec_kernel(const unsigned short* __restrict__ Whb, const float* __restrict__ a,
                              float* __restrict__ es, float* __restrict__ ed)
{
    int wave = threadIdx.x >> 6, lane = threadIdx.x & 63;
    int idx = blockIdx.x * 4 + wave;   // idx = h*NN + n
    int h = idx >> 12, n = idx & 4095;
    const unsigned short* row = Whb + (size_t)n * DCAT + h * DH + lane * 4;
    const float* ah = a + h * 2 * DH + lane * 4;
    s16x4 wv = *(const s16x4*)row;
    f32x4 a1 = *(const f32x4*)ah;
    f32x4 a2 = *(const f32x4*)(ah + DH);
    float s1 = 0.f, s2 = 0.f;
#pragma unroll
    for (int j = 0; j < 4; ++j) {
        float wf = bf2f((unsigned short)wv[j]);
        s1 = fmaf(a1[j], wf, s1);
        s2 = fmaf(a2[j], wf, s2);
    }
#pragma unroll
    for (int off = 32; off; off >>= 1) {
        s1 += __shfl_down(s1, off);
        s2 += __shfl_down(s2, off);
    }
    if (lane == 0) { es[idx] = s1; ed[idx] = s2; }
}

// ------------------------------------------------------------------
// Per-edge weights + denominators
// ------------------------------------------------------------------
__global__ void edge_kernel(const int* __restrict__ src, const int* __restrict__ dst,
                            const float* __restrict__ es, const float* __restrict__ ed,
                            float* __restrict__ wmin, float* __restrict__ dacc)
{
    int e = blockIdx.x * 256 + threadIdx.x;
    int s = src[e], d = dst[e];
#pragma unroll
    for (int h = 0; h < HH; ++h) {
        float v = es[h * NN + s] + ed[h * NN + d];
        v = v > 0.f ? v : ALPHA_LR * v;
        float w = expm1f(v);
        wmin[h * EE + e] = w;
        atomicAdd(&dacc[h * NN + s], w);
    }
}

__global__ void denom_kernel(const float* __restrict__ dacc, float* __restrict__ invd)
{
    int i = blockIdx.x * 256 + threadIdx.x;
    invd[i] = 1.f / ((float)NN + dacc[i]);
}

__global__ void reduce_add_kernel(const float* __restrict__ v, int n, float* __restrict__ out)
{
    float s = 0.f;
    for (int i = blockIdx.x * blockDim.x + threadIdx.x; i < n; i += gridDim.x * blockDim.x)
        s += v[i];
#pragma unroll
    for (int off = 32; off; off >>= 1) s += __shfl_down(s, off);
    __shared__ float red[4];
    if ((threadIdx.x & 63) == 0) red[threadIdx.x >> 6] = s;
    __syncthreads();
    if (threadIdx.x == 0) atomicAdd(out, red[0] + red[1] + red[2] + red[3]);
}

__global__ void imp_kernel(const int* __restrict__ src, const int* __restrict__ dst,
                           const float* __restrict__ wmin, const float* __restrict__ invd,
                           float* __restrict__ imp)
{
    int e = blockIdx.x * 256 + threadIdx.x;
    int s = src[e], d = dst[e];
    float t = wmin[e] * invd[s]
            + wmin[EE + e] * invd[NN + s]
            + wmin[2 * EE + e] * invd[2 * NN + s]
            + wmin[3 * EE + e] * invd[3 * NN + s];
    atomicAdd(&imp[d], t);
}

// column sums of Wh per head (Wh [n][h*256+o] bf16)
__global__ void colsum_kernel(const unsigned short* __restrict__ Whb, float* __restrict__ csum)
{
    int h = blockIdx.x >> 5;
    int chunk = blockIdx.x & 31;
    int o = threadIdx.x;
    float s = 0.f;
    for (int n = chunk * 128; n < chunk * 128 + 128; ++n)
        s += bf2f(Whb[(size_t)n * DCAT + h * DH + o]);
    atomicAdd(&csum[h * DH + o], s);
}

// ------------------------------------------------------------------
// CSR build
// ------------------------------------------------------------------
__global__ void count_kernel(const int* __restrict__ src, int* __restrict__ counts)
{
    int e = blockIdx.x * 256 + threadIdx.x;
    atomicAdd(&counts[src[e]], 1);
}

__global__ void scan_kernel(const int* __restrict__ counts, int* __restrict__ rowptr)
{
    __shared__ int lsum[1024];
    int t = threadIdx.x;
    int base = t * 4;
    int c0 = counts[base], c1 = counts[base + 1], c2 = counts[base + 2], c3 = counts[base + 3];
    int s = c0 + c1 + c2 + c3;
    lsum[t] = s;
    __syncthreads();
    for (int off = 1; off < 1024; off <<= 1) {
        int v = (t >= off) ? lsum[t - off] : 0;
        __syncthreads();
        lsum[t] += v;
        __syncthreads();
    }
    int excl = lsum[t] - s;
    rowptr[base] = excl;
    rowptr[base + 1] = excl + c0;
    rowptr[base + 2] = excl + c0 + c1;
    rowptr[base + 3] = excl + c0 + c1 + c2;
    if (t == 1023) rowptr[NN] = lsum[1023];
}

__global__ void copy_int_kernel(const int* __restrict__ a, int* __restrict__ b, int n)
{
    int i = blockIdx.x * 256 + threadIdx.x;
    if (i < n) b[i] = a[i];
}

__global__ void fill_kernel(const int* __restrict__ src, const int* __restrict__ dst,
                            int* __restrict__ cursor, int2* __restrict__ cde)
{
    int e = blockIdx.x * 256 + threadIdx.x;
    int s = src[e];
    int pos = atomicAdd(&cursor[s], 1);
    cde[pos] = make_int2(dst[e], e);
}

// ------------------------------------------------------------------
// Aggregation: block per node; 4 waves split the edge list; lane owns
// 4 outputs/head (16 f32 acc); cross-wave combine in LDS.
// ------------------------------------------------------------------
__global__ __launch_bounds__(256)
void agg_kernel(const unsigned short* __restrict__ Whb, const float* __restrict__ wmin,
                const float* __restrict__ invd, const float* __restrict__ csum,
                const int* __restrict__ rowptr, const int2* __restrict__ cde,
                unsigned short* __restrict__ hb_out, float* __restrict__ hf_out)
{
    __shared__ float red[4 * DCAT];
    const int n = blockIdx.x;
    const int w = threadIdx.x >> 6, lane = threadIdx.x & 63;
    float acc[4][4] = {};
    const int beg = rowptr[n], end = rowptr[n + 1];
    const unsigned short* base = Whb + lane * 4;

#define AGG_EDGE(p)                                                             \
    {                                                                           \
        int2 de = cde[p];                                                       \
        float wh0 = wmin[de.y];                                                 \
        float wh1 = wmin[EE + de.y];                                            \
        float wh2 = wmin[2 * EE + de.y];                                        \
        float wh3 = wmin[3 * EE + de.y];                                        \
        const unsigned short* row = base + (size_t)de.x * DCAT;                 \
        s16x4 v0 = *(const s16x4*)(row);                                        \
        s16x4 v1 = *(const s16x4*)(row + DH);                                   \
        s16x4 v2 = *(const s16x4*)(row + 2 * DH);                               \
        s16x4 v3 = *(const s16x4*)(row + 3 * DH);                               \
        _Pragma("unroll")                                                       \
        for (int j = 0; j < 4; ++j) {                                           \
            acc[0][j] = fmaf(wh0, bf2f((unsigned short)v0[j]), acc[0][j]);      \
            acc[1][j] = fmaf(wh1, bf2f((unsigned short)v1[j]), acc[1][j]);      \
            acc[2][j] = fmaf(wh2, bf2f((unsigned short)v2[j]), acc[2][j]);      \
            acc[3][j] = fmaf(wh3, bf2f((unsigned short)v3[j]), acc[3][j]);      \
        }                                                                       \
    }

    int p = beg + w;
    for (; p + 4 < end; p += 8) { AGG_EDGE(p); AGG_EDGE(p + 4); }
    if (p < end) AGG_EDGE(p);
#undef AGG_EDGE

#pragma unroll
    for (int h = 0; h < 4; ++h)
        *(f32x4*)(&red[w * DCAT + h * DH + lane * 4]) =
            (f32x4){acc[h][0], acc[h][1], acc[h][2], acc[h][3]};
    __syncthreads();

    const int t = threadIdx.x;           // outputs i = 4t..4t+3 (i = h*256+o)
    f32x4 s0 = *(const f32x4*)(&red[t * 4]);
    f32x4 s1 = *(const f32x4*)(&red[DCAT + t * 4]);
    f32x4 s2 = *(const f32x4*)(&red[2 * DCAT + t * 4]);
    f32x4 s3 = *(const f32x4*)(&red[3 * DCAT + t * 4]);
    const int h = t >> 6;
    const float iv = invd[h * NN + n];
    f32x4 cs = *(const f32x4*)(&csum[t * 4]);
    f32x4 r;
    s16x4 ob;
#pragma unroll
    for (int j = 0; j < 4; ++j) {
        float v = (cs[j] + s0[j] + s1[j] + s2[j] + s3[j]) * iv;
        v = v > 0.f ? v : expm1f(v);
        r[j] = v;
        ob[j] = (short)f2bf(v);
    }
    size_t rb = (size_t)n * DCAT + t * 4;
    *(s16x4*)(&hb_out[rb]) = ob;
    if (hf_out) *(f32x4*)(&hf_out[rb]) = r;
}

// ------------------------------------------------------------------
// Pooling + classifier (fp32 h3)
// ------------------------------------------------------------------
__global__ void pool_score_kernel(const float* __restrict__ h3, const float* __restrict__ pw,
                                  const float* __restrict__ pb, float* __restrict__ ps)
{
    int wave = threadIdx.x >> 6, lane = threadIdx.x & 63;
    int n = blockIdx.x * 4 + wave;
    const float* row = h3 + (size_t)n * DCAT;
    float s = 0.f;
    for (int i = lane; i < DCAT; i += 64) s = fmaf(row[i], pw[i], s);
#pragma unroll
    for (int off = 32; off; off >>= 1) s += __shfl_down(s, off);
    if (lane == 0) ps[n] = s + pb[0];
}

__global__ void softmax_n_kernel(const float* __restrict__ s, float* __restrict__ aw)
{
    __shared__ float red[16];
    __shared__ float MM, SS;
    int t = threadIdx.x;
    float m = -1e30f;
    for (int i = t; i < NN; i += 1024) m = fmaxf(m, s[i]);
#pragma unroll
    for (int off = 32; off; off >>= 1) m = fmaxf(m, __shfl_down(m, off));
    if ((t & 63) == 0) red[t >> 6] = m;
    __syncthreads();
    if (t == 0) {
        float v = red[0];
        for (int i = 1; i < 16; ++i) v = fmaxf(v, red[i]);
        MM = v;
    }
    __syncthreads();
    float sum = 0.f;
    for (int i = t; i < NN; i += 1024) sum += expf(s[i] - MM);
#pragma unroll
    for (int off = 32; off; off >>= 1) sum += __shfl_down(sum, off);
    __syncthreads();
    if ((t & 63) == 0) red[t >> 6] = sum;
    __syncthreads();
    if (t == 0) {
        float v = 0.f;
        for (int i = 0; i < 16; ++i) v += red[i];
        SS = v;
    }
    __syncthreads();
    for (int i = t; i < NN; i += 1024) aw[i] = expf(s[i] - MM) / SS;
}

__global__ void emb_kernel(const float* __restrict__ h3, const float* __restrict__ aw,
                           float* __restrict__ emb)
{
    int o = blockIdx.x * 256 + threadIdx.x;
    int n0 = blockIdx.y * 256;
    float s = 0.f;
    for (int n = n0; n < n0 + 256; ++n) s = fmaf(aw[n], h3[(size_t)n * DCAT + o], s);
    atomicAdd(&emb[o], s);
}

__global__ void classifier_kernel(const float* __restrict__ emb, const float* __restrict__ c1w,
                                  const float* __restrict__ c1b, const float* __restrict__ c2w,
                                  const float* __restrict__ c2b, float* __restrict__ out)
{
    __shared__ float z[DH];
    __shared__ float lg[8];
    int t = threadIdx.x;
    float acc = c1b[t];
    for (int i = 0; i < DCAT; ++i) acc = fmaf(emb[i], c1w[(size_t)i * DH + t], acc);
    z[t] = acc > 0.f ? acc : 0.f;
    __syncthreads();
    if (t < 7) {
        float l = c2b[t];
        for (int i = 0; i < DH; ++i) l = fmaf(z[i], c2w[i * 7 + t], l);
        lg[t] = l;
    }
    __syncthreads();
    if (t == 0) {
        float m = lg[0];
        for (int i = 1; i < 7; ++i) m = fmaxf(m, lg[i]);
        float sm = 0.f, ex[7];
        for (int i = 0; i < 7; ++i) { ex[i] = expf(lg[i] - m); sm += ex[i]; }
        for (int i = 0; i < 7; ++i) out[i] = ex[i] / sm;
    }
}

__global__ void natt_kernel(const float* __restrict__ imp, const float* __restrict__ Ctot,
                            float* __restrict__ out)
{
    int m = blockIdx.x * 256 + threadIdx.x;
    out[7 + m] = (imp[m] + Ctot[0]) * (1.0f / 12.0f);
}

// ------------------------------------------------------------------
extern "C" void kernel_launch(void* const* d_in, const int* in_sizes, int n_in,
                              void* d_out, int out_size, void* d_ws, size_t ws_size,
                              hipStream_t stream)
{
    const float* x   = (const float*)d_in[0];
    const int*   ei  = (const int*)d_in[1];
    const float* Wp  = (const float*)d_in[2];
    const float* bp  = (const float*)d_in[3];
    const float* W[3]  = {(const float*)d_in[4], (const float*)d_in[6], (const float*)d_in[8]};
    const float* av[3] = {(const float*)d_in[5], (const float*)d_in[7], (const float*)d_in[9]};
    const float* pw  = (const float*)d_in[10];
    const float* pb  = (const float*)d_in[11];
    const float* c1w = (const float*)d_in[12];
    const float* c1b = (const float*)d_in[13];
    const float* c2w = (const float*)d_in[14];
    const float* c2b = (const float*)d_in[15];
    float* out = (float*)d_out;
    (void)in_sizes; (void)n_in; (void)out_size; (void)ws_size;

    char* base = (char*)d_ws;
    size_t off = 0;
    auto alloc = [&](size_t bytes) -> void* {
        void* p = base + off;
        off = (off + bytes + 255) & ~(size_t)255;
        return p;
    };
    unsigned short* xb   = (unsigned short*)alloc((size_t)NN * DIN * 2);
    unsigned short* BTp  = (unsigned short*)alloc((size_t)DH * DIN * 2);
    unsigned short* BT0  = (unsigned short*)alloc((size_t)DCAT * DH * 2);
    unsigned short* BT1  = (unsigned short*)alloc((size_t)DCAT * DCAT * 2);
    unsigned short* BT2  = (unsigned short*)alloc((size_t)DCAT * DCAT * 2);
    unsigned short* Whb  = (unsigned short*)alloc((size_t)NN * DCAT * 2);
    unsigned short* hb0  = (unsigned short*)alloc((size_t)NN * DCAT * 2);
    unsigned short* hb1  = (unsigned short*)alloc((size_t)NN * DCAT * 2);
    float* hf    = (float*)alloc((size_t)NN * DCAT * 4);
    float* wmin  = (float*)alloc((size_t)HH * EE * 4);
    float* es    = (float*)alloc(HH * NN * 4);
    float* ed    = (float*)alloc(HH * NN * 4);
    float* dacc  = (float*)alloc(HH * NN * 4);
    float* invd  = (float*)alloc(HH * NN * 4);
    float* csum  = (float*)alloc(HH * DH * 4);
    float* imp   = (float*)alloc(NN * 4);
    float* Ctot  = (float*)alloc(256);
    int*   counts = (int*)alloc(NN * 4);
    int*   rowptr = (int*)alloc((NN + 1) * 4);
    int*   cursor = (int*)alloc(NN * 4);
    int2*  cde    = (int2*)alloc((size_t)EE * 8);
    float* ps    = (float*)alloc(NN * 4);
    float* paw   = (float*)alloc(NN * 4);
    float* emb   = (float*)alloc(DCAT * 4);

    const int* srcp = ei;
    const int* dstp = ei + EE;

    hipMemsetAsync(imp, 0, NN * 4, stream);
    hipMemsetAsync(Ctot, 0, 256, stream);
    hipMemsetAsync(counts, 0, NN * 4, stream);
    hipMemsetAsync(emb, 0, DCAT * 4, stream);

    // CSR build
    count_kernel<<<EE / 256, 256, 0, stream>>>(srcp, counts);
    scan_kernel<<<1, 1024, 0, stream>>>(counts, rowptr);
    copy_int_kernel<<<NN / 256, 256, 0, stream>>>(rowptr, cursor, NN);
    fill_kernel<<<EE / 256, 256, 0, stream>>>(srcp, dstp, cursor, cde);

    // casts / repacks
    cast_kernel<<<(NN * DIN / 4 + 255) / 256, 256, 0, stream>>>(x, xb, NN * DIN / 4);
    transpose_cast_kernel<<<dim3(DIN / 32, 8, 1), 256, 0, stream>>>(Wp, BTp, DIN);
    transpose_cast_kernel<<<dim3(DH / 32, 8, HH), 256, 0, stream>>>(W[0], BT0, DH);
    transpose_cast_kernel<<<dim3(DCAT / 32, 8, HH), 256, 0, stream>>>(W[1], BT1, DCAT);
    transpose_cast_kernel<<<dim3(DCAT / 32, 8, HH), 256, 0, stream>>>(W[2], BT2, DCAT);

    // projection: hb0[N][256] = relu(x @ Wp + bp)
    mfma_gemm_kernel<<<dim3(NN / 128, DH / 128), 256, 0, stream>>>(
        xb, BTp, DIN, hb0, nullptr, DH, bp, 1);

    unsigned short* cur = hb0;
    unsigned short* nxt = hb1;
    const unsigned short* BTl[3] = {BT0, BT1, BT2};
    for (int layer = 0; layer < 3; ++layer) {
        int K = (layer == 0) ? DH : DCAT;
        mfma_gemm_kernel<<<dim3(NN / 128, DCAT / 128), 256, 0, stream>>>(
            cur, BTl[layer], K, Whb, nullptr, DCAT, nullptr, 0);
        attvec_kernel<<<HH * NN / 4, 256, 0, stream>>>(Whb, av[layer], es, ed);
        hipMemsetAsync(dacc, 0, HH * NN * 4, stream);
        hipMemsetAsync(csum, 0, HH * DH * 4, stream);
        edge_kernel<<<EE / 256, 256, 0, stream>>>(srcp, dstp, es, ed, wmin, dacc);
        denom_kernel<<<HH * NN / 256, 256, 0, stream>>>(dacc, invd);
        reduce_add_kernel<<<16, 256, 0, stream>>>(invd, HH * NN, Ctot);
        imp_kernel<<<EE / 256, 256, 0, stream>>>(srcp, dstp, wmin, invd, imp);
        colsum_kernel<<<HH * 32, 256, 0, stream>>>(Whb, csum);
        agg_kernel<<<NN, 256, 0, stream>>>(Whb, wmin, invd, csum, rowptr, cde, nxt,
                                           (layer == 2) ? hf : nullptr);
        unsigned short* t = cur; cur = nxt; nxt = t;
    }

    // pooling + classifier on fp32 h3
    pool_score_kernel<<<NN / 4, 256, 0, stream>>>(hf, pw, pb, ps);
    softmax_n_kernel<<<1, 1024, 0, stream>>>(ps, paw);
    emb_kernel<<<dim3(DCAT / 256, NN / 256), 256, 0, stream>>>(hf, paw, emb);
    classifier_kernel<<<1, 256, 0, stream>>>(emb, c1w, c1b, c2w, c2b, out);
    natt_kernel<<<NN / 256, 256, 0, stream>>>(imp, Ctot, out);
}

// Round 4
// 390.425 us; speedup vs baseline: 2.8318x; 1.2729x over previous
//
#include <hip/hip_runtime.h>
#include <hip/hip_bf16.h>
#include <math.h>

#define NN   4096
#define EE   131072
#define HH   4
#define DIN  128
#define DH   256
#define DCAT 1024   /* HH*DH */
#define ALPHA_LR 0.2f

typedef __attribute__((ext_vector_type(8))) short  short8;
typedef __attribute__((ext_vector_type(4))) short  s16x4;
typedef __attribute__((ext_vector_type(4))) float  f32x4;

__device__ __forceinline__ unsigned short f2bf(float f) {
    union { float f; unsigned u; } v; v.f = f;
    unsigned r = v.u + 0x7fffu + ((v.u >> 16) & 1u);
    return (unsigned short)(r >> 16);
}
__device__ __forceinline__ float bf2f(unsigned short us) {
    union { unsigned u; float f; } v; v.u = ((unsigned)us) << 16;
    return v.f;
}

// ------------------------------------------------------------------
// cast fp32 -> bf16, 4 elems/thread
// ------------------------------------------------------------------
__global__ void cast_kernel(const float* __restrict__ in, unsigned short* __restrict__ out, int n4)
{
    int i = blockIdx.x * 256 + threadIdx.x;
    if (i < n4) {
        f32x4 v = *(const f32x4*)(in + (size_t)i * 4);
        s16x4 o;
        o[0] = (short)f2bf(v[0]); o[1] = (short)f2bf(v[1]);
        o[2] = (short)f2bf(v[2]); o[3] = (short)f2bf(v[3]);
        *(s16x4*)(out + (size_t)i * 4) = o;
    }
}

// ------------------------------------------------------------------
// transpose+cast: W[h][K][256] fp32 -> BT[h*256+o][K] bf16
// ------------------------------------------------------------------
__global__ void transpose_cast_kernel(const float* __restrict__ W, unsigned short* __restrict__ BT, int K)
{
    __shared__ float tile[32][33];
    int h = blockIdx.z;
    int k0 = blockIdx.x * 32, o0 = blockIdx.y * 32;
    int tx = threadIdx.x & 31, ty = threadIdx.x >> 5;
    const float* Ws = W + (size_t)h * K * 256;
#pragma unroll
    for (int i = 0; i < 32; i += 8)
        tile[ty + i][tx] = Ws[(size_t)(k0 + ty + i) * 256 + o0 + tx];
    __syncthreads();
#pragma unroll
    for (int i = 0; i < 32; i += 8)
        BT[(size_t)(h * 256 + o0 + ty + i) * K + k0 + tx] = f2bf(tile[tx][ty + i]);
}

// W1/W2 combined (z<4 -> W1, else W2), K = DCAT
__global__ void transpose_cast2_kernel(const float* __restrict__ W1, const float* __restrict__ W2,
                                       unsigned short* __restrict__ BT1, unsigned short* __restrict__ BT2)
{
    __shared__ float tile[32][33];
    int z = blockIdx.z;
    int h = z & 3;
    const float* W = (z < 4) ? W1 : W2;
    unsigned short* BT = (z < 4) ? BT1 : BT2;
    int k0 = blockIdx.x * 32, o0 = blockIdx.y * 32;
    int tx = threadIdx.x & 31, ty = threadIdx.x >> 5;
    const float* Ws = W + (size_t)h * DCAT * 256;
#pragma unroll
    for (int i = 0; i < 32; i += 8)
        tile[ty + i][tx] = Ws[(size_t)(k0 + ty + i) * 256 + o0 + tx];
    __syncthreads();
#pragma unroll
    for (int i = 0; i < 32; i += 8)
        BT[(size_t)(h * 256 + o0 + ty + i) * DCAT + k0 + tx] = f2bf(tile[tx][ty + i]);
}

// ------------------------------------------------------------------
// bf16 MFMA GEMM: C = act(A[M][K] @ BT[N][K]^T + bias), 128x128 tile.
// Optional fused epilogue (av != null, ldc must be DCAT):
//   es[h*NN+row] += sum_o a[h][o]*C[row][h*256+o]   (fp32 accum)
//   ed[h*NN+row] += sum_o a[h][256+o]*C[row][...]
//   csum[col]    += sum_rows C[row][col]
// ------------------------------------------------------------------
__global__ __launch_bounds__(256)
void mfma_gemm_kernel(const unsigned short* __restrict__ A,
                      const unsigned short* __restrict__ BT,
                      int K,
                      unsigned short* __restrict__ Cb,
                      float* __restrict__ Cf,
                      int ldc,
                      const float* __restrict__ bias, int relu_act,
                      const float* __restrict__ av,
                      float* __restrict__ es, float* __restrict__ ed,
                      float* __restrict__ csum)
{
    __shared__ __align__(16) unsigned short sA[2][128 * 32];
    __shared__ __align__(16) unsigned short sB[2][128 * 32];

    const int tid = threadIdx.x;
    const int w = tid >> 6, l = tid & 63;
    const int wr = w >> 1, wc = w & 1;
    const int row0 = blockIdx.x * 128, col0 = blockIdx.y * 128;
    const int lrow = l >> 2;
    const int lce  = (l & 3) * 8;
    const int lr = l & 15, lg = l >> 4;

    f32x4 acc[4][4];
#pragma unroll
    for (int m = 0; m < 4; ++m)
#pragma unroll
        for (int n = 0; n < 4; ++n)
            acc[m][n] = (f32x4){0.f, 0.f, 0.f, 0.f};

#define STAGE(buf, k0)                                                          \
    {                                                                           \
        _Pragma("unroll")                                                       \
        for (int p = 0; p < 2; ++p) {                                           \
            int chunk = w * 2 + p;                                              \
            int r = chunk * 16 + lrow;                                          \
            const unsigned short* ga = A  + (size_t)(row0 + r) * K + (k0) + lce;\
            const unsigned short* gb = BT + (size_t)(col0 + r) * K + (k0) + lce;\
            __builtin_amdgcn_global_load_lds(                                   \
                (const __attribute__((address_space(1))) unsigned int*)ga,      \
                (__attribute__((address_space(3))) unsigned int*)(&sA[buf][chunk * 512]), \
                16, 0, 0);                                                      \
            __builtin_amdgcn_global_load_lds(                                   \
                (const __attribute__((address_space(1))) unsigned int*)gb,      \
                (__attribute__((address_space(3))) unsigned int*)(&sB[buf][chunk * 512]), \
                16, 0, 0);                                                      \
        }                                                                       \
    }

#define COMPUTE(buf)                                                            \
    {                                                                           \
        short8 af[4], bfr[4];                                                   \
        _Pragma("unroll")                                                       \
        for (int m = 0; m < 4; ++m) {                                           \
            int r = wr * 64 + m * 16 + lr;                                      \
            af[m] = *(const short8*)(&sA[buf][r * 32 + lg * 8]);                \
        }                                                                       \
        _Pragma("unroll")                                                       \
        for (int n = 0; n < 4; ++n) {                                           \
            int r = wc * 64 + n * 16 + lr;                                      \
            bfr[n] = *(const short8*)(&sB[buf][r * 32 + lg * 8]);               \
        }                                                                       \
        _Pragma("unroll")                                                       \
        for (int m = 0; m < 4; ++m)                                             \
            _Pragma("unroll")                                                   \
            for (int n = 0; n < 4; ++n)                                         \
                acc[m][n] = __builtin_amdgcn_mfma_f32_16x16x32_bf16(            \
                    af[m], bfr[n], acc[m][n], 0, 0, 0);                         \
    }

    STAGE(0, 0);
    __syncthreads();
    int nt = K >> 5, cur = 0;
    for (int t = 0; t < nt - 1; ++t) {
        STAGE(cur ^ 1, (t + 1) * 32);
        COMPUTE(cur);
        __syncthreads();
        cur ^= 1;
    }
    COMPUTE(cur);
#undef STAGE
#undef COMPUTE

    // C-write
#pragma unroll
    for (int m = 0; m < 4; ++m) {
        int rbase = row0 + wr * 64 + m * 16 + lg * 4;
#pragma unroll
        for (int n = 0; n < 4; ++n) {
            int c = col0 + wc * 64 + n * 16 + lr;
            float bv = bias ? bias[c] : 0.f;
#pragma unroll
            for (int r = 0; r < 4; ++r) {
                float v = acc[m][n][r] + bv;
                if (relu_act) v = fmaxf(v, 0.f);
                size_t idx = (size_t)(rbase + r) * ldc + c;
                if (Cb) Cb[idx] = f2bf(v);
                if (Cf) Cf[idx] = v;
            }
        }
    }

    // fused attvec + colsum epilogue
    if (av) {
        const int h = (col0 + wc * 64) >> 8;   // head uniform per wave quadrant
        float aes[4], aed[4];
#pragma unroll
        for (int n = 0; n < 4; ++n) {
            int cc = (col0 + wc * 64 + n * 16 + lr) & 255;
            aes[n] = av[h * 2 * DH + cc];
            aed[n] = av[h * 2 * DH + DH + cc];
        }
#pragma unroll
        for (int m = 0; m < 4; ++m) {
#pragma unroll
            for (int r = 0; r < 4; ++r) {
                float se = 0.f, sd = 0.f;
#pragma unroll
                for (int n = 0; n < 4; ++n) {
                    se = fmaf(aes[n], acc[m][n][r], se);
                    sd = fmaf(aed[n], acc[m][n][r], sd);
                }
                se += __shfl_xor(se, 1);  sd += __shfl_xor(sd, 1);
                se += __shfl_xor(se, 2);  sd += __shfl_xor(sd, 2);
                se += __shfl_xor(se, 4);  sd += __shfl_xor(sd, 4);
                se += __shfl_xor(se, 8);  sd += __shfl_xor(sd, 8);
                if (lr == 0) {
                    int row = row0 + wr * 64 + m * 16 + lg * 4 + r;
                    atomicAdd(&es[h * NN + row], se);
                    atomicAdd(&ed[h * NN + row], sd);
                }
            }
        }
#pragma unroll
        for (int n = 0; n < 4; ++n) {
            float s = 0.f;
#pragma unroll
            for (int m = 0; m < 4; ++m)
#pragma unroll
                for (int r = 0; r < 4; ++r)
                    s += acc[m][n][r];
            s += __shfl_xor(s, 16);
            s += __shfl_xor(s, 32);
            if (lg == 0) atomicAdd(&csum[col0 + wc * 64 + n * 16 + lr], s);
        }
    }
}

// ------------------------------------------------------------------
// Per-edge weights (packed [E][4]) + denominators
// ------------------------------------------------------------------
__global__ void edge_kernel(const int* __restrict__ src, const int* __restrict__ dst,
                            const float* __restrict__ es, const float* __restrict__ ed,
                            f32x4* __restrict__ wmin4, float* __restrict__ dacc)
{
    int e = blockIdx.x * 256 + threadIdx.x;
    int s = src[e], d = dst[e];
    f32x4 w;
#pragma unroll
    for (int h = 0; h < HH; ++h) {
        float v = es[h * NN + s] + ed[h * NN + d];
        v = v > 0.f ? v : ALPHA_LR * v;
        w[h] = expm1f(v);
        atomicAdd(&dacc[h * NN + s], w[h]);
    }
    wmin4[e] = w;
}

// invd = 1/(N+dacc); Ctot += sum(invd)
__global__ void denom_reduce_kernel(const float* __restrict__ dacc, float* __restrict__ invd,
                                    float* __restrict__ Ctot)
{
    int i = blockIdx.x * 256 + threadIdx.x;
    float v = 1.f / ((float)NN + dacc[i]);
    invd[i] = v;
    float s = v;
#pragma unroll
    for (int off = 32; off; off >>= 1) s += __shfl_down(s, off);
    __shared__ float red[4];
    if ((threadIdx.x & 63) == 0) red[threadIdx.x >> 6] = s;
    __syncthreads();
    if (threadIdx.x == 0) atomicAdd(Ctot, red[0] + red[1] + red[2] + red[3]);
}

// ------------------------------------------------------------------
// CSR build
// ------------------------------------------------------------------
__global__ void count_kernel(const int* __restrict__ src, int* __restrict__ counts)
{
    int e = blockIdx.x * 256 + threadIdx.x;
    atomicAdd(&counts[src[e]], 1);
}

__global__ void scan_kernel(const int* __restrict__ counts, int* __restrict__ rowptr,
                            int* __restrict__ cursor)
{
    __shared__ int lsum[1024];
    int t = threadIdx.x;
    int base = t * 4;
    int c0 = counts[base], c1 = counts[base + 1], c2 = counts[base + 2], c3 = counts[base + 3];
    int s = c0 + c1 + c2 + c3;
    lsum[t] = s;
    __syncthreads();
    for (int off = 1; off < 1024; off <<= 1) {
        int v = (t >= off) ? lsum[t - off] : 0;
        __syncthreads();
        lsum[t] += v;
        __syncthreads();
    }
    int excl = lsum[t] - s;
    rowptr[base] = excl;          cursor[base] = excl;
    rowptr[base + 1] = excl + c0; cursor[base + 1] = excl + c0;
    rowptr[base + 2] = excl + c0 + c1; cursor[base + 2] = excl + c0 + c1;
    rowptr[base + 3] = excl + c0 + c1 + c2; cursor[base + 3] = excl + c0 + c1 + c2;
    if (t == 1023) rowptr[NN] = lsum[1023];
}

__global__ void fill_kernel(const int* __restrict__ src, const int* __restrict__ dst,
                            int* __restrict__ cursor, int2* __restrict__ cde)
{
    int e = blockIdx.x * 256 + threadIdx.x;
    int s = src[e];
    int pos = atomicAdd(&cursor[s], 1);
    cde[pos] = make_int2(dst[e], e);
}

// ------------------------------------------------------------------
// Aggregation (+ fused importance scatter): block per node; 4 waves
// split the edge list; lane owns 4 outputs/head; LDS combine.
// ------------------------------------------------------------------
__global__ __launch_bounds__(256)
void agg_kernel(const unsigned short* __restrict__ Whb, const f32x4* __restrict__ wmin4,
                const float* __restrict__ invd, const float* __restrict__ csum,
                const int* __restrict__ rowptr, const int2* __restrict__ cde,
                float* __restrict__ imp,
                unsigned short* __restrict__ hb_out, float* __restrict__ hf_out)
{
    __shared__ float red[4 * DCAT];
    const int n = blockIdx.x;
    const int w = threadIdx.x >> 6, lane = threadIdx.x & 63;
    const float iv0 = invd[n], iv1 = invd[NN + n], iv2 = invd[2 * NN + n], iv3 = invd[3 * NN + n];
    float acc[4][4] = {};
    const int beg = rowptr[n], end = rowptr[n + 1];
    const unsigned short* base = Whb + lane * 4;

#define AGG_EDGE(p)                                                             \
    {                                                                           \
        int2 de = cde[p];                                                       \
        f32x4 wv = wmin4[de.y];                                                 \
        const unsigned short* row = base + (size_t)de.x * DCAT;                 \
        s16x4 v0 = *(const s16x4*)(row);                                        \
        s16x4 v1 = *(const s16x4*)(row + DH);                                   \
        s16x4 v2 = *(const s16x4*)(row + 2 * DH);                               \
        s16x4 v3 = *(const s16x4*)(row + 3 * DH);                               \
        if (lane == 0)                                                          \
            atomicAdd(&imp[de.x],                                               \
                      fmaf(wv[0], iv0, fmaf(wv[1], iv1,                         \
                      fmaf(wv[2], iv2, wv[3] * iv3))));                         \
        _Pragma("unroll")                                                       \
        for (int j = 0; j < 4; ++j) {                                           \
            acc[0][j] = fmaf(wv[0], bf2f((unsigned short)v0[j]), acc[0][j]);    \
            acc[1][j] = fmaf(wv[1], bf2f((unsigned short)v1[j]), acc[1][j]);    \
            acc[2][j] = fmaf(wv[2], bf2f((unsigned short)v2[j]), acc[2][j]);    \
            acc[3][j] = fmaf(wv[3], bf2f((unsigned short)v3[j]), acc[3][j]);    \
        }                                                                       \
    }

    int p = beg + w;
    for (; p + 4 < end; p += 8) { AGG_EDGE(p); AGG_EDGE(p + 4); }
    if (p < end) AGG_EDGE(p);
#undef AGG_EDGE

#pragma unroll
    for (int h = 0; h < 4; ++h)
        *(f32x4*)(&red[w * DCAT + h * DH + lane * 4]) =
            (f32x4){acc[h][0], acc[h][1], acc[h][2], acc[h][3]};
    __syncthreads();

    const int t = threadIdx.x;           // outputs i = 4t..4t+3 (i = h*256+o)
    f32x4 s0 = *(const f32x4*)(&red[t * 4]);
    f32x4 s1 = *(const f32x4*)(&red[DCAT + t * 4]);
    f32x4 s2 = *(const f32x4*)(&red[2 * DCAT + t * 4]);
    f32x4 s3 = *(const f32x4*)(&red[3 * DCAT + t * 4]);
    const int h = t >> 6;
    const float iv = invd[h * NN + n];
    f32x4 cs = *(const f32x4*)(&csum[t * 4]);
    f32x4 r;
    s16x4 ob;
#pragma unroll
    for (int j = 0; j < 4; ++j) {
        float v = (cs[j] + s0[j] + s1[j] + s2[j] + s3[j]) * iv;
        v = v > 0.f ? v : expm1f(v);
        r[j] = v;
        ob[j] = (short)f2bf(v);
    }
    size_t rb = (size_t)n * DCAT + t * 4;
    *(s16x4*)(&hb_out[rb]) = ob;
    if (hf_out) *(f32x4*)(&hf_out[rb]) = r;
}

// ------------------------------------------------------------------
// Pooling + classifier
// ------------------------------------------------------------------
__global__ void pool_score_kernel(const float* __restrict__ h3, const float* __restrict__ pw,
                                  const float* __restrict__ pb, float* __restrict__ ps)
{
    int wave = threadIdx.x >> 6, lane = threadIdx.x & 63;
    int n = blockIdx.x * 4 + wave;
    const float* row = h3 + (size_t)n * DCAT;
    float s = 0.f;
    for (int i = lane; i < DCAT; i += 64) s = fmaf(row[i], pw[i], s);
#pragma unroll
    for (int off = 32; off; off >>= 1) s += __shfl_down(s, off);
    if (lane == 0) ps[n] = s + pb[0];
}

__global__ void softmax_n_kernel(const float* __restrict__ s, float* __restrict__ aw)
{
    __shared__ float red[16];
    __shared__ float MM, SS;
    int t = threadIdx.x;
    float m = -1e30f;
    for (int i = t; i < NN; i += 1024) m = fmaxf(m, s[i]);
#pragma unroll
    for (int off = 32; off; off >>= 1) m = fmaxf(m, __shfl_down(m, off));
    if ((t & 63) == 0) red[t >> 6] = m;
    __syncthreads();
    if (t == 0) {
        float v = red[0];
        for (int i = 1; i < 16; ++i) v = fmaxf(v, red[i]);
        MM = v;
    }
    __syncthreads();
    float sum = 0.f;
    for (int i = t; i < NN; i += 1024) sum += expf(s[i] - MM);
#pragma unroll
    for (int off = 32; off; off >>= 1) sum += __shfl_down(sum, off);
    __syncthreads();
    if ((t & 63) == 0) red[t >> 6] = sum;
    __syncthreads();
    if (t == 0) {
        float v = 0.f;
        for (int i = 0; i < 16; ++i) v += red[i];
        SS = v;
    }
    __syncthreads();
    for (int i = t; i < NN; i += 1024) aw[i] = expf(s[i] - MM) / SS;
}

__global__ void emb_kernel(const float* __restrict__ h3, const float* __restrict__ aw,
                           float* __restrict__ emb)
{
    int o = blockIdx.x * 256 + threadIdx.x;
    int n0 = blockIdx.y * 256;
    float s = 0.f;
    for (int n = n0; n < n0 + 256; ++n) s = fmaf(aw[n], h3[(size_t)n * DCAT + o], s);
    atomicAdd(&emb[o], s);
}

// split-K matvec: zbuf[t] += sum_{j in block-chunk} emb[j]*c1w[j][t]
__global__ void c1_kernel(const float* __restrict__ emb, const float* __restrict__ c1w,
                          float* __restrict__ zbuf)
{
    int t = threadIdx.x;
    int r0 = blockIdx.x * 32;
    float s = 0.f;
#pragma unroll
    for (int j = 0; j < 32; ++j)
        s = fmaf(emb[r0 + j], c1w[(size_t)(r0 + j) * DH + t], s);
    atomicAdd(&zbuf[t], s);
}

__global__ void c2_kernel(const float* __restrict__ zbuf, const float* __restrict__ c1b,
                          const float* __restrict__ c2w, const float* __restrict__ c2b,
                          float* __restrict__ out)
{
    __shared__ float z[DH];
    __shared__ float lgs[8];
    int t = threadIdx.x;
    z[t] = fmaxf(zbuf[t] + c1b[t], 0.f);
    __syncthreads();
    int g = t >> 5, k = t & 31;
    if (g < 7) {
        float s = 0.f;
#pragma unroll
        for (int j = 0; j < 8; ++j)
            s = fmaf(z[k + 32 * j], c2w[(k + 32 * j) * 7 + g], s);
#pragma unroll
        for (int off = 16; off; off >>= 1) s += __shfl_down(s, off, 32);
        if (k == 0) lgs[g] = s + c2b[g];
    }
    __syncthreads();
    if (t == 0) {
        float m = lgs[0];
        for (int i = 1; i < 7; ++i) m = fmaxf(m, lgs[i]);
        float sm = 0.f, ex[7];
        for (int i = 0; i < 7; ++i) { ex[i] = expf(lgs[i] - m); sm += ex[i]; }
        for (int i = 0; i < 7; ++i) out[i] = ex[i] / sm;
    }
}

__global__ void natt_kernel(const float* __restrict__ imp, const float* __restrict__ Ctot,
                            float* __restrict__ out)
{
    int m = blockIdx.x * 256 + threadIdx.x;
    out[7 + m] = (imp[m] + Ctot[0]) * (1.0f / 12.0f);
}

// ------------------------------------------------------------------
extern "C" void kernel_launch(void* const* d_in, const int* in_sizes, int n_in,
                              void* d_out, int out_size, void* d_ws, size_t ws_size,
                              hipStream_t stream)
{
    const float* x   = (const float*)d_in[0];
    const int*   ei  = (const int*)d_in[1];
    const float* Wp  = (const float*)d_in[2];
    const float* bp  = (const float*)d_in[3];
    const float* W[3]  = {(const float*)d_in[4], (const float*)d_in[6], (const float*)d_in[8]};
    const float* av[3] = {(const float*)d_in[5], (const float*)d_in[7], (const float*)d_in[9]};
    const float* pw  = (const float*)d_in[10];
    const float* pb  = (const float*)d_in[11];
    const float* c1w = (const float*)d_in[12];
    const float* c1b = (const float*)d_in[13];
    const float* c2w = (const float*)d_in[14];
    const float* c2b = (const float*)d_in[15];
    float* out = (float*)d_out;
    (void)in_sizes; (void)n_in; (void)out_size; (void)ws_size;

    char* base = (char*)d_ws;
    size_t off = 0;
    auto alloc = [&](size_t bytes) -> void* {
        void* p = base + off;
        off = (off + bytes + 255) & ~(size_t)255;
        return p;
    };
    // ---- zero region (single memset covers [zero_begin, zero_end)) ----
    size_t zero_begin = off;
    float* es3   = (float*)alloc((size_t)3 * HH * NN * 4);
    float* ed3   = (float*)alloc((size_t)3 * HH * NN * 4);
    float* dacc3 = (float*)alloc((size_t)3 * HH * NN * 4);
    float* csum3 = (float*)alloc((size_t)3 * DCAT * 4);
    float* imp   = (float*)alloc(NN * 4);
    float* Ctot  = (float*)alloc(256);
    int*   counts = (int*)alloc(NN * 4);
    float* emb   = (float*)alloc(DCAT * 4);
    float* zbuf  = (float*)alloc(DH * 4);
    size_t zero_bytes = off - zero_begin;
    // ---- rest ----
    unsigned short* xb   = (unsigned short*)alloc((size_t)NN * DIN * 2);
    unsigned short* BTp  = (unsigned short*)alloc((size_t)DH * DIN * 2);
    unsigned short* BT0  = (unsigned short*)alloc((size_t)DCAT * DH * 2);
    unsigned short* BT1  = (unsigned short*)alloc((size_t)DCAT * DCAT * 2);
    unsigned short* BT2  = (unsigned short*)alloc((size_t)DCAT * DCAT * 2);
    unsigned short* Whb  = (unsigned short*)alloc((size_t)NN * DCAT * 2);
    unsigned short* hb0  = (unsigned short*)alloc((size_t)NN * DCAT * 2);
    unsigned short* hb1  = (unsigned short*)alloc((size_t)NN * DCAT * 2);
    float* hf    = (float*)alloc((size_t)NN * DCAT * 4);
    f32x4* wmin4 = (f32x4*)alloc((size_t)EE * 16);
    float* invd  = (float*)alloc(HH * NN * 4);
    int*   rowptr = (int*)alloc((NN + 1) * 4);
    int*   cursor = (int*)alloc(NN * 4);
    int2*  cde    = (int2*)alloc((size_t)EE * 8);
    float* ps    = (float*)alloc(NN * 4);
    float* paw   = (float*)alloc(NN * 4);

    const int* srcp = ei;
    const int* dstp = ei + EE;

    hipMemsetAsync(base + zero_begin, 0, zero_bytes, stream);

    // CSR build
    count_kernel<<<EE / 256, 256, 0, stream>>>(srcp, counts);
    scan_kernel<<<1, 1024, 0, stream>>>(counts, rowptr, cursor);
    fill_kernel<<<EE / 256, 256, 0, stream>>>(srcp, dstp, cursor, cde);

    // casts / repacks
    cast_kernel<<<(NN * DIN / 4 + 255) / 256, 256, 0, stream>>>(x, xb, NN * DIN / 4);
    transpose_cast_kernel<<<dim3(DIN / 32, 8, 1), 256, 0, stream>>>(Wp, BTp, DIN);
    transpose_cast_kernel<<<dim3(DH / 32, 8, HH), 256, 0, stream>>>(W[0], BT0, DH);
    transpose_cast2_kernel<<<dim3(DCAT / 32, 8, 8), 256, 0, stream>>>(W[1], W[2], BT1, BT2);

    // projection: hb0[N][256] = relu(x @ Wp + bp)
    mfma_gemm_kernel<<<dim3(NN / 128, DH / 128), 256, 0, stream>>>(
        xb, BTp, DIN, hb0, nullptr, DH, bp, 1, nullptr, nullptr, nullptr, nullptr);

    unsigned short* cur = hb0;
    unsigned short* nxt = hb1;
    const unsigned short* BTl[3] = {BT0, BT1, BT2};
    for (int layer = 0; layer < 3; ++layer) {
        int K = (layer == 0) ? DH : DCAT;
        float* es = es3 + (size_t)layer * HH * NN;
        float* ed = ed3 + (size_t)layer * HH * NN;
        float* dacc = dacc3 + (size_t)layer * HH * NN;
        float* csum = csum3 + (size_t)layer * DCAT;
        mfma_gemm_kernel<<<dim3(NN / 128, DCAT / 128), 256, 0, stream>>>(
            cur, BTl[layer], K, Whb, nullptr, DCAT, nullptr, 0, av[layer], es, ed, csum);
        edge_kernel<<<EE / 256, 256, 0, stream>>>(srcp, dstp, es, ed, wmin4, dacc);
        denom_reduce_kernel<<<HH * NN / 256, 256, 0, stream>>>(dacc, invd, Ctot);
        agg_kernel<<<NN, 256, 0, stream>>>(Whb, wmin4, invd, csum, rowptr, cde, imp, nxt,
                                           (layer == 2) ? hf : nullptr);
        unsigned short* t = cur; cur = nxt; nxt = t;
    }

    // pooling + classifier
    pool_score_kernel<<<NN / 4, 256, 0, stream>>>(hf, pw, pb, ps);
    softmax_n_kernel<<<1, 1024, 0, stream>>>(ps, paw);
    emb_kernel<<<dim3(DCAT / 256, NN / 256), 256, 0, stream>>>(hf, paw, emb);
    c1_kernel<<<32, 256, 0, stream>>>(emb, c1w, zbuf);
    c2_kernel<<<1, 256, 0, stream>>>(zbuf, c1b, c2w, c2b, out);
    natt_kernel<<<NN / 256, 256, 0, stream>>>(imp, Ctot, out);
}

// Round 5
// 368.912 us; speedup vs baseline: 2.9969x; 1.0583x over previous
//
#include <hip/hip_runtime.h>
#include <hip/hip_bf16.h>
#include <math.h>

#define NN   4096
#define EE   131072
#define HH   4
#define DIN  128
#define DH   256
#define DCAT 1024   /* HH*DH */
#define ALPHA_LR 0.2f
#define MAXDEG 128  /* degree cap for LDS stash; fallback recompute beyond */

typedef __attribute__((ext_vector_type(8))) short  short8;
typedef __attribute__((ext_vector_type(4))) short  s16x4;
typedef __attribute__((ext_vector_type(4))) float  f32x4;

__device__ __forceinline__ unsigned short f2bf(float f) {
    union { float f; unsigned u; } v; v.f = f;
    unsigned r = v.u + 0x7fffu + ((v.u >> 16) & 1u);
    return (unsigned short)(r >> 16);
}
__device__ __forceinline__ float bf2f(unsigned short us) {
    union { unsigned u; float f; } v; v.u = ((unsigned)us) << 16;
    return v.f;
}

// ------------------------------------------------------------------
// cast fp32 -> bf16, 4 elems/thread
// ------------------------------------------------------------------
__global__ void cast_kernel(const float* __restrict__ in, unsigned short* __restrict__ out, int n4)
{
    int i = blockIdx.x * 256 + threadIdx.x;
    if (i < n4) {
        f32x4 v = *(const f32x4*)(in + (size_t)i * 4);
        s16x4 o;
        o[0] = (short)f2bf(v[0]); o[1] = (short)f2bf(v[1]);
        o[2] = (short)f2bf(v[2]); o[3] = (short)f2bf(v[3]);
        *(s16x4*)(out + (size_t)i * 4) = o;
    }
}

// ------------------------------------------------------------------
// transpose+cast: W[h][K][256] fp32 -> BT[h*256+o][K] bf16
// ------------------------------------------------------------------
__global__ void transpose_cast_kernel(const float* __restrict__ W, unsigned short* __restrict__ BT, int K)
{
    __shared__ float tile[32][33];
    int h = blockIdx.z;
    int k0 = blockIdx.x * 32, o0 = blockIdx.y * 32;
    int tx = threadIdx.x & 31, ty = threadIdx.x >> 5;
    const float* Ws = W + (size_t)h * K * 256;
#pragma unroll
    for (int i = 0; i < 32; i += 8)
        tile[ty + i][tx] = Ws[(size_t)(k0 + ty + i) * 256 + o0 + tx];
    __syncthreads();
#pragma unroll
    for (int i = 0; i < 32; i += 8)
        BT[(size_t)(h * 256 + o0 + ty + i) * K + k0 + tx] = f2bf(tile[tx][ty + i]);
}

// W1/W2 combined (z<4 -> W1, else W2), K = DCAT
__global__ void transpose_cast2_kernel(const float* __restrict__ W1, const float* __restrict__ W2,
                                       unsigned short* __restrict__ BT1, unsigned short* __restrict__ BT2)
{
    __shared__ float tile[32][33];
    int z = blockIdx.z;
    int h = z & 3;
    const float* W = (z < 4) ? W1 : W2;
    unsigned short* BT = (z < 4) ? BT1 : BT2;
    int k0 = blockIdx.x * 32, o0 = blockIdx.y * 32;
    int tx = threadIdx.x & 31, ty = threadIdx.x >> 5;
    const float* Ws = W + (size_t)h * DCAT * 256;
#pragma unroll
    for (int i = 0; i < 32; i += 8)
        tile[ty + i][tx] = Ws[(size_t)(k0 + ty + i) * 256 + o0 + tx];
    __syncthreads();
#pragma unroll
    for (int i = 0; i < 32; i += 8)
        BT[(size_t)(h * 256 + o0 + ty + i) * DCAT + k0 + tx] = f2bf(tile[tx][ty + i]);
}

// ------------------------------------------------------------------
// bf16 MFMA GEMM: C = act(A[M][K] @ BT[N][K]^T + bias), 128x128 tile.
// Optional fused epilogue (av != null, ldc must be DCAT):
//   es4[row][h] += sum_o a[h][o]   * C[row][h*256+o]
//   ed4[row][h] += sum_o a[h][256+o]*C[row][h*256+o]
//   csum[col]   += sum_rows C[row][col]
// ------------------------------------------------------------------
__global__ __launch_bounds__(256)
void mfma_gemm_kernel(const unsigned short* __restrict__ A,
                      const unsigned short* __restrict__ BT,
                      int K,
                      unsigned short* __restrict__ Cb,
                      int ldc,
                      const float* __restrict__ bias, int relu_act,
                      const float* __restrict__ av,
                      float* __restrict__ es4, float* __restrict__ ed4,
                      float* __restrict__ csum)
{
    __shared__ __align__(16) unsigned short sA[2][128 * 32];
    __shared__ __align__(16) unsigned short sB[2][128 * 32];

    const int tid = threadIdx.x;
    const int w = tid >> 6, l = tid & 63;
    const int wr = w >> 1, wc = w & 1;
    const int row0 = blockIdx.x * 128, col0 = blockIdx.y * 128;
    const int lrow = l >> 2;
    const int lce  = (l & 3) * 8;
    const int lr = l & 15, lg = l >> 4;

    f32x4 acc[4][4];
#pragma unroll
    for (int m = 0; m < 4; ++m)
#pragma unroll
        for (int n = 0; n < 4; ++n)
            acc[m][n] = (f32x4){0.f, 0.f, 0.f, 0.f};

#define STAGE(buf, k0)                                                          \
    {                                                                           \
        _Pragma("unroll")                                                       \
        for (int p = 0; p < 2; ++p) {                                           \
            int chunk = w * 2 + p;                                              \
            int r = chunk * 16 + lrow;                                          \
            const unsigned short* ga = A  + (size_t)(row0 + r) * K + (k0) + lce;\
            const unsigned short* gb = BT + (size_t)(col0 + r) * K + (k0) + lce;\
            __builtin_amdgcn_global_load_lds(                                   \
                (const __attribute__((address_space(1))) unsigned int*)ga,      \
                (__attribute__((address_space(3))) unsigned int*)(&sA[buf][chunk * 512]), \
                16, 0, 0);                                                      \
            __builtin_amdgcn_global_load_lds(                                   \
                (const __attribute__((address_space(1))) unsigned int*)gb,      \
                (__attribute__((address_space(3))) unsigned int*)(&sB[buf][chunk * 512]), \
                16, 0, 0);                                                      \
        }                                                                       \
    }

#define COMPUTE(buf)                                                            \
    {                                                                           \
        short8 af[4], bfr[4];                                                   \
        _Pragma("unroll")                                                       \
        for (int m = 0; m < 4; ++m) {                                           \
            int r = wr * 64 + m * 16 + lr;                                      \
            af[m] = *(const short8*)(&sA[buf][r * 32 + lg * 8]);                \
        }                                                                       \
        _Pragma("unroll")                                                       \
        for (int n = 0; n < 4; ++n) {                                           \
            int r = wc * 64 + n * 16 + lr;                                      \
            bfr[n] = *(const short8*)(&sB[buf][r * 32 + lg * 8]);               \
        }                                                                       \
        _Pragma("unroll")                                                       \
        for (int m = 0; m < 4; ++m)                                             \
            _Pragma("unroll")                                                   \
            for (int n = 0; n < 4; ++n)                                         \
                acc[m][n] = __builtin_amdgcn_mfma_f32_16x16x32_bf16(            \
                    af[m], bfr[n], acc[m][n], 0, 0, 0);                         \
    }

    STAGE(0, 0);
    __syncthreads();
    int nt = K >> 5, cur = 0;
    for (int t = 0; t < nt - 1; ++t) {
        STAGE(cur ^ 1, (t + 1) * 32);
        COMPUTE(cur);
        __syncthreads();
        cur ^= 1;
    }
    COMPUTE(cur);
#undef STAGE
#undef COMPUTE

    // C-write
#pragma unroll
    for (int m = 0; m < 4; ++m) {
        int rbase = row0 + wr * 64 + m * 16 + lg * 4;
#pragma unroll
        for (int n = 0; n < 4; ++n) {
            int c = col0 + wc * 64 + n * 16 + lr;
            float bv = bias ? bias[c] : 0.f;
#pragma unroll
            for (int r = 0; r < 4; ++r) {
                float v = acc[m][n][r] + bv;
                if (relu_act) v = fmaxf(v, 0.f);
                Cb[(size_t)(rbase + r) * ldc + c] = f2bf(v);
            }
        }
    }

    // fused attvec + colsum epilogue
    if (av) {
        const int h = (col0 + wc * 64) >> 8;   // head uniform per wave quadrant
        float aes[4], aed[4];
#pragma unroll
        for (int n = 0; n < 4; ++n) {
            int cc = (col0 + wc * 64 + n * 16 + lr) & 255;
            aes[n] = av[h * 2 * DH + cc];
            aed[n] = av[h * 2 * DH + DH + cc];
        }
#pragma unroll
        for (int m = 0; m < 4; ++m) {
#pragma unroll
            for (int r = 0; r < 4; ++r) {
                float se = 0.f, sd = 0.f;
#pragma unroll
                for (int n = 0; n < 4; ++n) {
                    se = fmaf(aes[n], acc[m][n][r], se);
                    sd = fmaf(aed[n], acc[m][n][r], sd);
                }
                se += __shfl_xor(se, 1);  sd += __shfl_xor(sd, 1);
                se += __shfl_xor(se, 2);  sd += __shfl_xor(sd, 2);
                se += __shfl_xor(se, 4);  sd += __shfl_xor(sd, 4);
                se += __shfl_xor(se, 8);  sd += __shfl_xor(sd, 8);
                if (lr == 0) {
                    int row = row0 + wr * 64 + m * 16 + lg * 4 + r;
                    atomicAdd(&es4[row * 4 + h], se);
                    atomicAdd(&ed4[row * 4 + h], sd);
                }
            }
        }
#pragma unroll
        for (int n = 0; n < 4; ++n) {
            float s = 0.f;
#pragma unroll
            for (int m = 0; m < 4; ++m)
#pragma unroll
                for (int r = 0; r < 4; ++r)
                    s += acc[m][n][r];
            s += __shfl_xor(s, 16);
            s += __shfl_xor(s, 32);
            if (lg == 0) atomicAdd(&csum[col0 + wc * 64 + n * 16 + lr], s);
        }
    }
}

// ------------------------------------------------------------------
// CSR build
// ------------------------------------------------------------------
__global__ void count_kernel(const int* __restrict__ src, int* __restrict__ counts)
{
    int e = blockIdx.x * 256 + threadIdx.x;
    atomicAdd(&counts[src[e]], 1);
}

__global__ void scan_kernel(const int* __restrict__ counts, int* __restrict__ rowptr,
                            int* __restrict__ cursor)
{
    __shared__ int lsum[1024];
    int t = threadIdx.x;
    int base = t * 4;
    int c0 = counts[base], c1 = counts[base + 1], c2 = counts[base + 2], c3 = counts[base + 3];
    int s = c0 + c1 + c2 + c3;
    lsum[t] = s;
    __syncthreads();
    for (int off = 1; off < 1024; off <<= 1) {
        int v = (t >= off) ? lsum[t - off] : 0;
        __syncthreads();
        lsum[t] += v;
        __syncthreads();
    }
    int excl = lsum[t] - s;
    rowptr[base] = excl;          cursor[base] = excl;
    rowptr[base + 1] = excl + c0; cursor[base + 1] = excl + c0;
    rowptr[base + 2] = excl + c0 + c1; cursor[base + 2] = excl + c0 + c1;
    rowptr[base + 3] = excl + c0 + c1 + c2; cursor[base + 3] = excl + c0 + c1 + c2;
    if (t == 1023) rowptr[NN] = lsum[1023];
}

__global__ void fill_kernel(const int* __restrict__ src, const int* __restrict__ dst,
                            int* __restrict__ cursor, int* __restrict__ cdst)
{
    int e = blockIdx.x * 256 + threadIdx.x;
    int s = src[e];
    int pos = atomicAdd(&cursor[s], 1);
    cdst[pos] = dst[e];
}

// ------------------------------------------------------------------
// Fused edge-weights + denominator + aggregation + importance:
// block per node n; 4 waves split its edge list; lane owns 4 outputs
// per head. w computed in-block from es/ed; invd derived in-block.
// ------------------------------------------------------------------
__global__ __launch_bounds__(256)
void agg_kernel(const unsigned short* __restrict__ Whb,
                const f32x4* __restrict__ es4, const f32x4* __restrict__ ed4,
                const float* __restrict__ csum,
                const int* __restrict__ rowptr, const int* __restrict__ cdst,
                float* __restrict__ imp, float* __restrict__ Ctot,
                unsigned short* __restrict__ hb_out)
{
    __shared__ float red[4 * DCAT];
    __shared__ f32x4 wlds[MAXDEG];
    __shared__ int   dlds[MAXDEG];
    __shared__ f32x4 swred[4];
    const int n = blockIdx.x;
    const int w = threadIdx.x >> 6, lane = threadIdx.x & 63;
    const int beg = rowptr[n], end = rowptr[n + 1];
    const f32x4 esv = es4[n];
    float acc[4][4] = {};
    f32x4 sw = (f32x4){0.f, 0.f, 0.f, 0.f};
    const unsigned short* basep = Whb + lane * 4;

    for (int p = beg + w; p < end; p += 4) {
        int d = cdst[p];
        f32x4 ev = ed4[d];
        const unsigned short* row = basep + (size_t)d * DCAT;
        s16x4 v0 = *(const s16x4*)(row);
        s16x4 v1 = *(const s16x4*)(row + DH);
        s16x4 v2 = *(const s16x4*)(row + 2 * DH);
        s16x4 v3 = *(const s16x4*)(row + 3 * DH);
        f32x4 wv;
#pragma unroll
        for (int h = 0; h < 4; ++h) {
            float v = esv[h] + ev[h];
            v = v > 0.f ? v : ALPHA_LR * v;
            wv[h] = expm1f(v);
            sw[h] += wv[h];
        }
        if (lane == 0) {
            int i = p - beg;
            if (i < MAXDEG) { wlds[i] = wv; dlds[i] = d; }
        }
#pragma unroll
        for (int j = 0; j < 4; ++j) {
            acc[0][j] = fmaf(wv[0], bf2f((unsigned short)v0[j]), acc[0][j]);
            acc[1][j] = fmaf(wv[1], bf2f((unsigned short)v1[j]), acc[1][j]);
            acc[2][j] = fmaf(wv[2], bf2f((unsigned short)v2[j]), acc[2][j]);
            acc[3][j] = fmaf(wv[3], bf2f((unsigned short)v3[j]), acc[3][j]);
        }
    }

    if (lane == 0) swred[w] = sw;
#pragma unroll
    for (int h = 0; h < 4; ++h)
        *(f32x4*)(&red[w * DCAT + h * DH + lane * 4]) =
            (f32x4){acc[h][0], acc[h][1], acc[h][2], acc[h][3]};
    __syncthreads();

    f32x4 invdv;
#pragma unroll
    for (int h = 0; h < 4; ++h)
        invdv[h] = 1.f / ((float)NN + swred[0][h] + swred[1][h] + swred[2][h] + swred[3][h]);
    if (threadIdx.x == 0)
        atomicAdd(Ctot, invdv[0] + invdv[1] + invdv[2] + invdv[3]);

    // importance scatter: imp[dst] += sum_h w[h]*invd[h]
    for (int idx = beg + (int)threadIdx.x; idx < end; idx += 256) {
        int i = idx - beg;
        f32x4 wv; int d;
        if (i < MAXDEG) { wv = wlds[i]; d = dlds[i]; }
        else {
            d = cdst[idx];
            f32x4 ev = ed4[d];
#pragma unroll
            for (int h = 0; h < 4; ++h) {
                float v = esv[h] + ev[h];
                v = v > 0.f ? v : ALPHA_LR * v;
                wv[h] = expm1f(v);
            }
        }
        atomicAdd(&imp[d], fmaf(wv[0], invdv[0], fmaf(wv[1], invdv[1],
                           fmaf(wv[2], invdv[2], wv[3] * invdv[3]))));
    }

    // finish: h'[n][i] for i = 4t..4t+3 (i = h*256+o)
    const int t = threadIdx.x;
    f32x4 s0 = *(const f32x4*)(&red[t * 4]);
    f32x4 s1 = *(const f32x4*)(&red[DCAT + t * 4]);
    f32x4 s2 = *(const f32x4*)(&red[2 * DCAT + t * 4]);
    f32x4 s3 = *(const f32x4*)(&red[3 * DCAT + t * 4]);
    const float iv = invdv[t >> 6];
    f32x4 cs = *(const f32x4*)(&csum[t * 4]);
    s16x4 ob;
#pragma unroll
    for (int j = 0; j < 4; ++j) {
        float v = (cs[j] + s0[j] + s1[j] + s2[j] + s3[j]) * iv;
        v = v > 0.f ? v : expm1f(v);
        ob[j] = (short)f2bf(v);
    }
    *(s16x4*)(&hb_out[(size_t)n * DCAT + t * 4]) = ob;
}

// ------------------------------------------------------------------
// Pooling + classifier (bf16 h3)
// ------------------------------------------------------------------
__global__ void pool_score_kernel(const unsigned short* __restrict__ h3, const float* __restrict__ pw,
                                  const float* __restrict__ pb, float* __restrict__ ps)
{
    int wave = threadIdx.x >> 6, lane = threadIdx.x & 63;
    int n = blockIdx.x * 4 + wave;
    const unsigned short* row = h3 + (size_t)n * DCAT;
    float s = 0.f;
#pragma unroll
    for (int i = 0; i < 4; ++i) {
        int o = (i * 64 + lane) * 4;
        s16x4 v = *(const s16x4*)(row + o);
        f32x4 a = *(const f32x4*)(pw + o);
#pragma unroll
        for (int j = 0; j < 4; ++j) s = fmaf(a[j], bf2f((unsigned short)v[j]), s);
    }
#pragma unroll
    for (int off = 32; off; off >>= 1) s += __shfl_down(s, off);
    if (lane == 0) ps[n] = s + pb[0];
}

__global__ void softmax_n_kernel(const float* __restrict__ s, float* __restrict__ aw)
{
    __shared__ float red[16];
    __shared__ float MM, SS;
    int t = threadIdx.x;
    float m = -1e30f;
    for (int i = t; i < NN; i += 1024) m = fmaxf(m, s[i]);
#pragma unroll
    for (int off = 32; off; off >>= 1) m = fmaxf(m, __shfl_down(m, off));
    if ((t & 63) == 0) red[t >> 6] = m;
    __syncthreads();
    if (t == 0) {
        float v = red[0];
        for (int i = 1; i < 16; ++i) v = fmaxf(v, red[i]);
        MM = v;
    }
    __syncthreads();
    float sum = 0.f;
    for (int i = t; i < NN; i += 1024) sum += expf(s[i] - MM);
#pragma unroll
    for (int off = 32; off; off >>= 1) sum += __shfl_down(sum, off);
    __syncthreads();
    if ((t & 63) == 0) red[t >> 6] = sum;
    __syncthreads();
    if (t == 0) {
        float v = 0.f;
        for (int i = 0; i < 16; ++i) v += red[i];
        SS = v;
    }
    __syncthreads();
    for (int i = t; i < NN; i += 1024) aw[i] = expf(s[i] - MM) / SS;
}

__global__ void emb_kernel(const unsigned short* __restrict__ h3, const float* __restrict__ aw,
                           float* __restrict__ emb)
{
    int o = blockIdx.x * 256 + threadIdx.x;
    int n0 = blockIdx.y * 256;
    float s = 0.f;
    for (int n = n0; n < n0 + 256; ++n)
        s = fmaf(aw[n], bf2f(h3[(size_t)n * DCAT + o]), s);
    atomicAdd(&emb[o], s);
}

// split-K matvec: zbuf[t] += sum_{j in block-chunk} emb[j]*c1w[j][t]
__global__ void c1_kernel(const float* __restrict__ emb, const float* __restrict__ c1w,
                          float* __restrict__ zbuf)
{
    int t = threadIdx.x;
    int r0 = blockIdx.x * 32;
    float s = 0.f;
#pragma unroll
    for (int j = 0; j < 32; ++j)
        s = fmaf(emb[r0 + j], c1w[(size_t)(r0 + j) * DH + t], s);
    atomicAdd(&zbuf[t], s);
}

__global__ void c2_kernel(const float* __restrict__ zbuf, const float* __restrict__ c1b,
                          const float* __restrict__ c2w, const float* __restrict__ c2b,
                          float* __restrict__ out)
{
    __shared__ float z[DH];
    __shared__ float lgs[8];
    int t = threadIdx.x;
    z[t] = fmaxf(zbuf[t] + c1b[t], 0.f);
    __syncthreads();
    int g = t >> 5, k = t & 31;
    if (g < 7) {
        float s = 0.f;
#pragma unroll
        for (int j = 0; j < 8; ++j)
            s = fmaf(z[k + 32 * j], c2w[(k + 32 * j) * 7 + g], s);
#pragma unroll
        for (int off = 16; off; off >>= 1) s += __shfl_down(s, off, 32);
        if (k == 0) lgs[g] = s + c2b[g];
    }
    __syncthreads();
    if (t == 0) {
        float m = lgs[0];
        for (int i = 1; i < 7; ++i) m = fmaxf(m, lgs[i]);
        float sm = 0.f, ex[7];
        for (int i = 0; i < 7; ++i) { ex[i] = expf(lgs[i] - m); sm += ex[i]; }
        for (int i = 0; i < 7; ++i) out[i] = ex[i] / sm;
    }
}

__global__ void natt_kernel(const float* __restrict__ imp, const float* __restrict__ Ctot,
                            float* __restrict__ out)
{
    int m = blockIdx.x * 256 + threadIdx.x;
    out[7 + m] = (imp[m] + Ctot[0]) * (1.0f / 12.0f);
}

// ------------------------------------------------------------------
extern "C" void kernel_launch(void* const* d_in, const int* in_sizes, int n_in,
                              void* d_out, int out_size, void* d_ws, size_t ws_size,
                              hipStream_t stream)
{
    const float* x   = (const float*)d_in[0];
    const int*   ei  = (const int*)d_in[1];
    const float* Wp  = (const float*)d_in[2];
    const float* bp  = (const float*)d_in[3];
    const float* W[3]  = {(const float*)d_in[4], (const float*)d_in[6], (const float*)d_in[8]};
    const float* av[3] = {(const float*)d_in[5], (const float*)d_in[7], (const float*)d_in[9]};
    const float* pw  = (const float*)d_in[10];
    const float* pb  = (const float*)d_in[11];
    const float* c1w = (const float*)d_in[12];
    const float* c1b = (const float*)d_in[13];
    const float* c2w = (const float*)d_in[14];
    const float* c2b = (const float*)d_in[15];
    float* out = (float*)d_out;
    (void)in_sizes; (void)n_in; (void)out_size; (void)ws_size;

    char* base = (char*)d_ws;
    size_t off = 0;
    auto alloc = [&](size_t bytes) -> void* {
        void* p = base + off;
        off = (off + bytes + 255) & ~(size_t)255;
        return p;
    };
    // ---- zero region (single memset) ----
    size_t zero_begin = off;
    float* es4_3 = (float*)alloc((size_t)3 * NN * 16);   // [layer][n][4]
    float* ed4_3 = (float*)alloc((size_t)3 * NN * 16);
    float* csum3 = (float*)alloc((size_t)3 * DCAT * 4);
    float* imp   = (float*)alloc(NN * 4);
    float* Ctot  = (float*)alloc(256);
    int*   counts = (int*)alloc(NN * 4);
    float* emb   = (float*)alloc(DCAT * 4);
    float* zbuf  = (float*)alloc(DH * 4);
    size_t zero_bytes = off - zero_begin;
    // ---- rest ----
    unsigned short* xb   = (unsigned short*)alloc((size_t)NN * DIN * 2);
    unsigned short* BTp  = (unsigned short*)alloc((size_t)DH * DIN * 2);
    unsigned short* BT0  = (unsigned short*)alloc((size_t)DCAT * DH * 2);
    unsigned short* BT1  = (unsigned short*)alloc((size_t)DCAT * DCAT * 2);
    unsigned short* BT2  = (unsigned short*)alloc((size_t)DCAT * DCAT * 2);
    unsigned short* Whb  = (unsigned short*)alloc((size_t)NN * DCAT * 2);
    unsigned short* hb0  = (unsigned short*)alloc((size_t)NN * DCAT * 2);
    unsigned short* hb1  = (unsigned short*)alloc((size_t)NN * DCAT * 2);
    int*   rowptr = (int*)alloc((NN + 1) * 4);
    int*   cursor = (int*)alloc(NN * 4);
    int*   cdst   = (int*)alloc((size_t)EE * 4);
    float* ps    = (float*)alloc(NN * 4);
    float* paw   = (float*)alloc(NN * 4);

    const int* srcp = ei;
    const int* dstp = ei + EE;

    hipMemsetAsync(base + zero_begin, 0, zero_bytes, stream);

    // CSR build
    count_kernel<<<EE / 256, 256, 0, stream>>>(srcp, counts);
    scan_kernel<<<1, 1024, 0, stream>>>(counts, rowptr, cursor);
    fill_kernel<<<EE / 256, 256, 0, stream>>>(srcp, dstp, cursor, cdst);

    // casts / repacks
    cast_kernel<<<(NN * DIN / 4 + 255) / 256, 256, 0, stream>>>(x, xb, NN * DIN / 4);
    transpose_cast_kernel<<<dim3(DIN / 32, 8, 1), 256, 0, stream>>>(Wp, BTp, DIN);
    transpose_cast_kernel<<<dim3(DH / 32, 8, HH), 256, 0, stream>>>(W[0], BT0, DH);
    transpose_cast2_kernel<<<dim3(DCAT / 32, 8, 8), 256, 0, stream>>>(W[1], W[2], BT1, BT2);

    // projection: hb0[N][256] = relu(x @ Wp + bp)
    mfma_gemm_kernel<<<dim3(NN / 128, DH / 128), 256, 0, stream>>>(
        xb, BTp, DIN, hb0, DH, bp, 1, nullptr, nullptr, nullptr, nullptr);

    unsigned short* cur = hb0;
    unsigned short* nxt = hb1;
    const unsigned short* BTl[3] = {BT0, BT1, BT2};
    for (int layer = 0; layer < 3; ++layer) {
        int K = (layer == 0) ? DH : DCAT;
        float* es = es4_3 + (size_t)layer * NN * 4;
        float* ed = ed4_3 + (size_t)layer * NN * 4;
        float* csum = csum3 + (size_t)layer * DCAT;
        mfma_gemm_kernel<<<dim3(NN / 128, DCAT / 128), 256, 0, stream>>>(
            cur, BTl[layer], K, Whb, DCAT, nullptr, 0, av[layer], es, ed, csum);
        agg_kernel<<<NN, 256, 0, stream>>>(Whb, (const f32x4*)es, (const f32x4*)ed,
                                           csum, rowptr, cdst, imp, Ctot, nxt);
        unsigned short* t = cur; cur = nxt; nxt = t;
    }

    // pooling + classifier on bf16 h3 (cur)
    pool_score_kernel<<<NN / 4, 256, 0, stream>>>(cur, pw, pb, ps);
    softmax_n_kernel<<<1, 1024, 0, stream>>>(ps, paw);
    emb_kernel<<<dim3(DCAT / 256, NN / 256), 256, 0, stream>>>(cur, paw, emb);
    c1_kernel<<<32, 256, 0, stream>>>(emb, c1w, zbuf);
    c2_kernel<<<1, 256, 0, stream>>>(zbuf, c1b, c2w, c2b, out);
    natt_kernel<<<NN / 256, 256, 0, stream>>>(imp, Ctot, out);
}

// Round 6
// 368.020 us; speedup vs baseline: 3.0042x; 1.0024x over previous
//
#include <hip/hip_runtime.h>
#include <hip/hip_bf16.h>
#include <math.h>

#define NN   4096
#define EE   131072
#define HH   4
#define DIN  128
#define DH   256
#define DCAT 1024   /* HH*DH */
#define ALPHA_LR 0.2f
#define MAXDEG 256  /* degree cap for LDS stash; fallback recompute beyond */

typedef __attribute__((ext_vector_type(8))) short  short8;
typedef __attribute__((ext_vector_type(4))) short  s16x4;
typedef __attribute__((ext_vector_type(4))) float  f32x4;

__device__ __forceinline__ unsigned short f2bf(float f) {
    union { float f; unsigned u; } v; v.f = f;
    unsigned r = v.u + 0x7fffu + ((v.u >> 16) & 1u);
    return (unsigned short)(r >> 16);
}
__device__ __forceinline__ float bf2f(unsigned short us) {
    union { unsigned u; float f; } v; v.u = ((unsigned)us) << 16;
    return v.f;
}

// ------------------------------------------------------------------
// cast fp32 -> bf16, 4 elems/thread
// ------------------------------------------------------------------
__global__ void cast_kernel(const float* __restrict__ in, unsigned short* __restrict__ out, int n4)
{
    int i = blockIdx.x * 256 + threadIdx.x;
    if (i < n4) {
        f32x4 v = *(const f32x4*)(in + (size_t)i * 4);
        s16x4 o;
        o[0] = (short)f2bf(v[0]); o[1] = (short)f2bf(v[1]);
        o[2] = (short)f2bf(v[2]); o[3] = (short)f2bf(v[3]);
        *(s16x4*)(out + (size_t)i * 4) = o;
    }
}

// ------------------------------------------------------------------
// transpose+cast: W[h][K][256] fp32 -> BT[h*256+o][K] bf16
// ------------------------------------------------------------------
__global__ void transpose_cast_kernel(const float* __restrict__ W, unsigned short* __restrict__ BT, int K)
{
    __shared__ float tile[32][33];
    int h = blockIdx.z;
    int k0 = blockIdx.x * 32, o0 = blockIdx.y * 32;
    int tx = threadIdx.x & 31, ty = threadIdx.x >> 5;
    const float* Ws = W + (size_t)h * K * 256;
#pragma unroll
    for (int i = 0; i < 32; i += 8)
        tile[ty + i][tx] = Ws[(size_t)(k0 + ty + i) * 256 + o0 + tx];
    __syncthreads();
#pragma unroll
    for (int i = 0; i < 32; i += 8)
        BT[(size_t)(h * 256 + o0 + ty + i) * K + k0 + tx] = f2bf(tile[tx][ty + i]);
}

// W1/W2 combined (z<4 -> W1, else W2), K = DCAT
__global__ void transpose_cast2_kernel(const float* __restrict__ W1, const float* __restrict__ W2,
                                       unsigned short* __restrict__ BT1, unsigned short* __restrict__ BT2)
{
    __shared__ float tile[32][33];
    int z = blockIdx.z;
    int h = z & 3;
    const float* W = (z < 4) ? W1 : W2;
    unsigned short* BT = (z < 4) ? BT1 : BT2;
    int k0 = blockIdx.x * 32, o0 = blockIdx.y * 32;
    int tx = threadIdx.x & 31, ty = threadIdx.x >> 5;
    const float* Ws = W + (size_t)h * DCAT * 256;
#pragma unroll
    for (int i = 0; i < 32; i += 8)
        tile[ty + i][tx] = Ws[(size_t)(k0 + ty + i) * 256 + o0 + tx];
    __syncthreads();
#pragma unroll
    for (int i = 0; i < 32; i += 8)
        BT[(size_t)(h * 256 + o0 + ty + i) * DCAT + k0 + tx] = f2bf(tile[tx][ty + i]);
}

// ------------------------------------------------------------------
// bf16 MFMA GEMM: C = act(A[M][K] @ BT[N][K]^T + bias), 128x128 tile.
// Optional fused epilogue (av != null, ldc must be DCAT):
//   es4[row][h] += sum_o a[h][o]   * C[row][h*256+o]
//   ed4[row][h] += sum_o a[h][256+o]*C[row][h*256+o]
//   csum[col]   += sum_rows C[row][col]
// ------------------------------------------------------------------
__global__ __launch_bounds__(256)
void mfma_gemm_kernel(const unsigned short* __restrict__ A,
                      const unsigned short* __restrict__ BT,
                      int K,
                      unsigned short* __restrict__ Cb,
                      int ldc,
                      const float* __restrict__ bias, int relu_act,
                      const float* __restrict__ av,
                      float* __restrict__ es4, float* __restrict__ ed4,
                      float* __restrict__ csum)
{
    __shared__ __align__(16) unsigned short sA[2][128 * 32];
    __shared__ __align__(16) unsigned short sB[2][128 * 32];

    const int tid = threadIdx.x;
    const int w = tid >> 6, l = tid & 63;
    const int wr = w >> 1, wc = w & 1;
    const int row0 = blockIdx.x * 128, col0 = blockIdx.y * 128;
    const int lrow = l >> 2;
    const int lce  = (l & 3) * 8;
    const int lr = l & 15, lg = l >> 4;

    f32x4 acc[4][4];
#pragma unroll
    for (int m = 0; m < 4; ++m)
#pragma unroll
        for (int n = 0; n < 4; ++n)
            acc[m][n] = (f32x4){0.f, 0.f, 0.f, 0.f};

#define STAGE(buf, k0)                                                          \
    {                                                                           \
        _Pragma("unroll")                                                       \
        for (int p = 0; p < 2; ++p) {                                           \
            int chunk = w * 2 + p;                                              \
            int r = chunk * 16 + lrow;                                          \
            const unsigned short* ga = A  + (size_t)(row0 + r) * K + (k0) + lce;\
            const unsigned short* gb = BT + (size_t)(col0 + r) * K + (k0) + lce;\
            __builtin_amdgcn_global_load_lds(                                   \
                (const __attribute__((address_space(1))) unsigned int*)ga,      \
                (__attribute__((address_space(3))) unsigned int*)(&sA[buf][chunk * 512]), \
                16, 0, 0);                                                      \
            __builtin_amdgcn_global_load_lds(                                   \
                (const __attribute__((address_space(1))) unsigned int*)gb,      \
                (__attribute__((address_space(3))) unsigned int*)(&sB[buf][chunk * 512]), \
                16, 0, 0);                                                      \
        }                                                                       \
    }

#define COMPUTE(buf)                                                            \
    {                                                                           \
        short8 af[4], bfr[4];                                                   \
        _Pragma("unroll")                                                       \
        for (int m = 0; m < 4; ++m) {                                           \
            int r = wr * 64 + m * 16 + lr;                                      \
            af[m] = *(const short8*)(&sA[buf][r * 32 + lg * 8]);                \
        }                                                                       \
        _Pragma("unroll")                                                       \
        for (int n = 0; n < 4; ++n) {                                           \
            int r = wc * 64 + n * 16 + lr;                                      \
            bfr[n] = *(const short8*)(&sB[buf][r * 32 + lg * 8]);               \
        }                                                                       \
        _Pragma("unroll")                                                       \
        for (int m = 0; m < 4; ++m)                                             \
            _Pragma("unroll")                                                   \
            for (int n = 0; n < 4; ++n)                                         \
                acc[m][n] = __builtin_amdgcn_mfma_f32_16x16x32_bf16(            \
                    af[m], bfr[n], acc[m][n], 0, 0, 0);                         \
    }

    STAGE(0, 0);
    __syncthreads();
    int nt = K >> 5, cur = 0;
    for (int t = 0; t < nt - 1; ++t) {
        STAGE(cur ^ 1, (t + 1) * 32);
        COMPUTE(cur);
        __syncthreads();
        cur ^= 1;
    }
    COMPUTE(cur);
#undef STAGE
#undef COMPUTE

    // C-write
#pragma unroll
    for (int m = 0; m < 4; ++m) {
        int rbase = row0 + wr * 64 + m * 16 + lg * 4;
#pragma unroll
        for (int n = 0; n < 4; ++n) {
            int c = col0 + wc * 64 + n * 16 + lr;
            float bv = bias ? bias[c] : 0.f;
#pragma unroll
            for (int r = 0; r < 4; ++r) {
                float v = acc[m][n][r] + bv;
                if (relu_act) v = fmaxf(v, 0.f);
                Cb[(size_t)(rbase + r) * ldc + c] = f2bf(v);
            }
        }
    }

    // fused attvec + colsum epilogue
    if (av) {
        const int h = (col0 + wc * 64) >> 8;   // head uniform per wave quadrant
        float aes[4], aed[4];
#pragma unroll
        for (int n = 0; n < 4; ++n) {
            int cc = (col0 + wc * 64 + n * 16 + lr) & 255;
            aes[n] = av[h * 2 * DH + cc];
            aed[n] = av[h * 2 * DH + DH + cc];
        }
#pragma unroll
        for (int m = 0; m < 4; ++m) {
#pragma unroll
            for (int r = 0; r < 4; ++r) {
                float se = 0.f, sd = 0.f;
#pragma unroll
                for (int n = 0; n < 4; ++n) {
                    se = fmaf(aes[n], acc[m][n][r], se);
                    sd = fmaf(aed[n], acc[m][n][r], sd);
                }
                se += __shfl_xor(se, 1);  sd += __shfl_xor(sd, 1);
                se += __shfl_xor(se, 2);  sd += __shfl_xor(sd, 2);
                se += __shfl_xor(se, 4);  sd += __shfl_xor(sd, 4);
                se += __shfl_xor(se, 8);  sd += __shfl_xor(sd, 8);
                if (lr == 0) {
                    int row = row0 + wr * 64 + m * 16 + lg * 4 + r;
                    atomicAdd(&es4[row * 4 + h], se);
                    atomicAdd(&ed4[row * 4 + h], sd);
                }
            }
        }
#pragma unroll
        for (int n = 0; n < 4; ++n) {
            float s = 0.f;
#pragma unroll
            for (int m = 0; m < 4; ++m)
#pragma unroll
                for (int r = 0; r < 4; ++r)
                    s += acc[m][n][r];
            s += __shfl_xor(s, 16);
            s += __shfl_xor(s, 32);
            if (lg == 0) atomicAdd(&csum[col0 + wc * 64 + n * 16 + lr], s);
        }
    }
}

// ------------------------------------------------------------------
// CSR build
// ------------------------------------------------------------------
__global__ void count_kernel(const int* __restrict__ src, int* __restrict__ counts)
{
    int e = blockIdx.x * 256 + threadIdx.x;
    atomicAdd(&counts[src[e]], 1);
}

__global__ void scan_kernel(const int* __restrict__ counts, int* __restrict__ rowptr,
                            int* __restrict__ cursor)
{
    __shared__ int lsum[1024];
    int t = threadIdx.x;
    int base = t * 4;
    int c0 = counts[base], c1 = counts[base + 1], c2 = counts[base + 2], c3 = counts[base + 3];
    int s = c0 + c1 + c2 + c3;
    lsum[t] = s;
    __syncthreads();
    for (int off = 1; off < 1024; off <<= 1) {
        int v = (t >= off) ? lsum[t - off] : 0;
        __syncthreads();
        lsum[t] += v;
        __syncthreads();
    }
    int excl = lsum[t] - s;
    rowptr[base] = excl;          cursor[base] = excl;
    rowptr[base + 1] = excl + c0; cursor[base + 1] = excl + c0;
    rowptr[base + 2] = excl + c0 + c1; cursor[base + 2] = excl + c0 + c1;
    rowptr[base + 3] = excl + c0 + c1 + c2; cursor[base + 3] = excl + c0 + c1 + c2;
    if (t == 1023) rowptr[NN] = lsum[1023];
}

__global__ void fill_kernel(const int* __restrict__ src, const int* __restrict__ dst,
                            int* __restrict__ cursor, int* __restrict__ cdst)
{
    int e = blockIdx.x * 256 + threadIdx.x;
    int s = src[e];
    int pos = atomicAdd(&cursor[s], 1);
    cdst[pos] = dst[e];
}

// ------------------------------------------------------------------
// Fused edge-weights + denominator + aggregation + importance.
// Phase A (edge-parallel): each thread computes wv for distinct edges
//   (4 expm1/edge total, not per-lane), stash in LDS, reduce denom.
// Phase B (gather): 4 waves, LDS-broadcast wv, pure load+fma.
// ------------------------------------------------------------------
__global__ __launch_bounds__(256)
void agg_kernel(const unsigned short* __restrict__ Whb,
                const f32x4* __restrict__ es4, const f32x4* __restrict__ ed4,
                const float* __restrict__ csum,
                const int* __restrict__ rowptr, const int* __restrict__ cdst,
                float* __restrict__ imp, float* __restrict__ Ctot,
                unsigned short* __restrict__ hb_out)
{
    __shared__ float red[4 * DCAT];      // 16 KB
    __shared__ f32x4 wlds[MAXDEG];       // 4 KB
    __shared__ int   dlds[MAXDEG];       // 1 KB
    __shared__ f32x4 swred[4];
    const int n = blockIdx.x;
    const int tid = threadIdx.x;
    const int w = tid >> 6, lane = tid & 63;
    const int beg = rowptr[n], end = rowptr[n + 1];
    const int deg = end - beg;
    const f32x4 esv = es4[n];

    // ---- Phase A: per-edge weights (each thread owns distinct edges) ----
    f32x4 sw = (f32x4){0.f, 0.f, 0.f, 0.f};
    for (int i = tid; i < deg; i += 256) {
        int d = cdst[beg + i];
        f32x4 ev = ed4[d];
        f32x4 wv;
#pragma unroll
        for (int h = 0; h < 4; ++h) {
            float v = esv[h] + ev[h];
            v = v > 0.f ? v : ALPHA_LR * v;
            wv[h] = expm1f(v);
            sw[h] += wv[h];
        }
        if (i < MAXDEG) { wlds[i] = wv; dlds[i] = d; }
    }
#pragma unroll
    for (int off = 32; off; off >>= 1) {
#pragma unroll
        for (int h = 0; h < 4; ++h) sw[h] += __shfl_down(sw[h], off);
    }
    if (lane == 0) swred[w] = sw;
    __syncthreads();

    f32x4 invdv;
#pragma unroll
    for (int h = 0; h < 4; ++h)
        invdv[h] = 1.f / ((float)NN + swred[0][h] + swred[1][h] + swred[2][h] + swred[3][h]);
    if (tid == 0)
        atomicAdd(Ctot, invdv[0] + invdv[1] + invdv[2] + invdv[3]);

    // importance scatter: imp[dst] += sum_h w[h]*invd[h]
    for (int i = tid; i < deg; i += 256) {
        f32x4 wv; int d;
        if (i < MAXDEG) { wv = wlds[i]; d = dlds[i]; }
        else {
            d = cdst[beg + i];
            f32x4 ev = ed4[d];
#pragma unroll
            for (int h = 0; h < 4; ++h) {
                float v = esv[h] + ev[h];
                v = v > 0.f ? v : ALPHA_LR * v;
                wv[h] = expm1f(v);
            }
        }
        atomicAdd(&imp[d], fmaf(wv[0], invdv[0], fmaf(wv[1], invdv[1],
                           fmaf(wv[2], invdv[2], wv[3] * invdv[3]))));
    }

    // ---- Phase B: weighted gather (4 waves split edges) ----
    float acc[4][4] = {};
    const unsigned short* basep = Whb + lane * 4;
    for (int i = w; i < deg; i += 4) {
        f32x4 wv; int d;
        if (i < MAXDEG) { wv = wlds[i]; d = dlds[i]; }   // LDS broadcast
        else {
            d = cdst[beg + i];
            f32x4 ev = ed4[d];
#pragma unroll
            for (int h = 0; h < 4; ++h) {
                float v = esv[h] + ev[h];
                v = v > 0.f ? v : ALPHA_LR * v;
                wv[h] = expm1f(v);
            }
        }
        const unsigned short* row = basep + (size_t)d * DCAT;
        s16x4 v0 = *(const s16x4*)(row);
        s16x4 v1 = *(const s16x4*)(row + DH);
        s16x4 v2 = *(const s16x4*)(row + 2 * DH);
        s16x4 v3 = *(const s16x4*)(row + 3 * DH);
#pragma unroll
        for (int j = 0; j < 4; ++j) {
            acc[0][j] = fmaf(wv[0], bf2f((unsigned short)v0[j]), acc[0][j]);
            acc[1][j] = fmaf(wv[1], bf2f((unsigned short)v1[j]), acc[1][j]);
            acc[2][j] = fmaf(wv[2], bf2f((unsigned short)v2[j]), acc[2][j]);
            acc[3][j] = fmaf(wv[3], bf2f((unsigned short)v3[j]), acc[3][j]);
        }
    }

#pragma unroll
    for (int h = 0; h < 4; ++h)
        *(f32x4*)(&red[w * DCAT + h * DH + lane * 4]) =
            (f32x4){acc[h][0], acc[h][1], acc[h][2], acc[h][3]};
    __syncthreads();

    // finish: h'[n][i] for i = 4t..4t+3 (i = h*256+o)
    f32x4 s0 = *(const f32x4*)(&red[tid * 4]);
    f32x4 s1 = *(const f32x4*)(&red[DCAT + tid * 4]);
    f32x4 s2 = *(const f32x4*)(&red[2 * DCAT + tid * 4]);
    f32x4 s3 = *(const f32x4*)(&red[3 * DCAT + tid * 4]);
    const float iv = invdv[tid >> 6];
    f32x4 cs = *(const f32x4*)(&csum[tid * 4]);
    s16x4 ob;
#pragma unroll
    for (int j = 0; j < 4; ++j) {
        float v = (cs[j] + s0[j] + s1[j] + s2[j] + s3[j]) * iv;
        v = v > 0.f ? v : expm1f(v);
        ob[j] = (short)f2bf(v);
    }
    *(s16x4*)(&hb_out[(size_t)n * DCAT + tid * 4]) = ob;
}

// ------------------------------------------------------------------
// Pooling + classifier (bf16 h3)
// ------------------------------------------------------------------
__global__ void pool_score_kernel(const unsigned short* __restrict__ h3, const float* __restrict__ pw,
                                  const float* __restrict__ pb, float* __restrict__ ps)
{
    int wave = threadIdx.x >> 6, lane = threadIdx.x & 63;
    int n = blockIdx.x * 4 + wave;
    const unsigned short* row = h3 + (size_t)n * DCAT;
    float s = 0.f;
#pragma unroll
    for (int i = 0; i < 4; ++i) {
        int o = (i * 64 + lane) * 4;
        s16x4 v = *(const s16x4*)(row + o);
        f32x4 a = *(const f32x4*)(pw + o);
#pragma unroll
        for (int j = 0; j < 4; ++j) s = fmaf(a[j], bf2f((unsigned short)v[j]), s);
    }
#pragma unroll
    for (int off = 32; off; off >>= 1) s += __shfl_down(s, off);
    if (lane == 0) ps[n] = s + pb[0];
}

__global__ void softmax_n_kernel(const float* __restrict__ s, float* __restrict__ aw)
{
    __shared__ float red[16];
    __shared__ float MM, SS;
    int t = threadIdx.x;
    float m = -1e30f;
    for (int i = t; i < NN; i += 1024) m = fmaxf(m, s[i]);
#pragma unroll
    for (int off = 32; off; off >>= 1) m = fmaxf(m, __shfl_down(m, off));
    if ((t & 63) == 0) red[t >> 6] = m;
    __syncthreads();
    if (t == 0) {
        float v = red[0];
        for (int i = 1; i < 16; ++i) v = fmaxf(v, red[i]);
        MM = v;
    }
    __syncthreads();
    float sum = 0.f;
    for (int i = t; i < NN; i += 1024) sum += expf(s[i] - MM);
#pragma unroll
    for (int off = 32; off; off >>= 1) sum += __shfl_down(sum, off);
    __syncthreads();
    if ((t & 63) == 0) red[t >> 6] = sum;
    __syncthreads();
    if (t == 0) {
        float v = 0.f;
        for (int i = 0; i < 16; ++i) v += red[i];
        SS = v;
    }
    __syncthreads();
    for (int i = t; i < NN; i += 1024) aw[i] = expf(s[i] - MM) / SS;
}

__global__ void emb_kernel(const unsigned short* __restrict__ h3, const float* __restrict__ aw,
                           float* __restrict__ emb)
{
    int o = blockIdx.x * 256 + threadIdx.x;
    int n0 = blockIdx.y * 256;
    float s = 0.f;
    for (int n = n0; n < n0 + 256; ++n)
        s = fmaf(aw[n], bf2f(h3[(size_t)n * DCAT + o]), s);
    atomicAdd(&emb[o], s);
}

// split-K matvec: zbuf[t] += sum_{j in block-chunk} emb[j]*c1w[j][t]
__global__ void c1_kernel(const float* __restrict__ emb, const float* __restrict__ c1w,
                          float* __restrict__ zbuf)
{
    int t = threadIdx.x;
    int r0 = blockIdx.x * 32;
    float s = 0.f;
#pragma unroll
    for (int j = 0; j < 32; ++j)
        s = fmaf(emb[r0 + j], c1w[(size_t)(r0 + j) * DH + t], s);
    atomicAdd(&zbuf[t], s);
}

__global__ void c2_kernel(const float* __restrict__ zbuf, const float* __restrict__ c1b,
                          const float* __restrict__ c2w, const float* __restrict__ c2b,
                          float* __restrict__ out)
{
    __shared__ float z[DH];
    __shared__ float lgs[8];
    int t = threadIdx.x;
    z[t] = fmaxf(zbuf[t] + c1b[t], 0.f);
    __syncthreads();
    int g = t >> 5, k = t & 31;
    if (g < 7) {
        float s = 0.f;
#pragma unroll
        for (int j = 0; j < 8; ++j)
            s = fmaf(z[k + 32 * j], c2w[(k + 32 * j) * 7 + g], s);
#pragma unroll
        for (int off = 16; off; off >>= 1) s += __shfl_down(s, off, 32);
        if (k == 0) lgs[g] = s + c2b[g];
    }
    __syncthreads();
    if (t == 0) {
        float m = lgs[0];
        for (int i = 1; i < 7; ++i) m = fmaxf(m, lgs[i]);
        float sm = 0.f, ex[7];
        for (int i = 0; i < 7; ++i) { ex[i] = expf(lgs[i] - m); sm += ex[i]; }
        for (int i = 0; i < 7; ++i) out[i] = ex[i] / sm;
    }
}

__global__ void natt_kernel(const float* __restrict__ imp, const float* __restrict__ Ctot,
                            float* __restrict__ out)
{
    int m = blockIdx.x * 256 + threadIdx.x;
    out[7 + m] = (imp[m] + Ctot[0]) * (1.0f / 12.0f);
}

// ------------------------------------------------------------------
extern "C" void kernel_launch(void* const* d_in, const int* in_sizes, int n_in,
                              void* d_out, int out_size, void* d_ws, size_t ws_size,
                              hipStream_t stream)
{
    const float* x   = (const float*)d_in[0];
    const int*   ei  = (const int*)d_in[1];
    const float* Wp  = (const float*)d_in[2];
    const float* bp  = (const float*)d_in[3];
    const float* W[3]  = {(const float*)d_in[4], (const float*)d_in[6], (const float*)d_in[8]};
    const float* av[3] = {(const float*)d_in[5], (const float*)d_in[7], (const float*)d_in[9]};
    const float* pw  = (const float*)d_in[10];
    const float* pb  = (const float*)d_in[11];
    const float* c1w = (const float*)d_in[12];
    const float* c1b = (const float*)d_in[13];
    const float* c2w = (const float*)d_in[14];
    const float* c2b = (const float*)d_in[15];
    float* out = (float*)d_out;
    (void)in_sizes; (void)n_in; (void)out_size; (void)ws_size;

    char* base = (char*)d_ws;
    size_t off = 0;
    auto alloc = [&](size_t bytes) -> void* {
        void* p = base + off;
        off = (off + bytes + 255) & ~(size_t)255;
        return p;
    };
    // ---- zero region (single memset) ----
    size_t zero_begin = off;
    float* es4_3 = (float*)alloc((size_t)3 * NN * 16);   // [layer][n][4]
    float* ed4_3 = (float*)alloc((size_t)3 * NN * 16);
    float* csum3 = (float*)alloc((size_t)3 * DCAT * 4);
    float* imp   = (float*)alloc(NN * 4);
    float* Ctot  = (float*)alloc(256);
    int*   counts = (int*)alloc(NN * 4);
    float* emb   = (float*)alloc(DCAT * 4);
    float* zbuf  = (float*)alloc(DH * 4);
    size_t zero_bytes = off - zero_begin;
    // ---- rest ----
    unsigned short* xb   = (unsigned short*)alloc((size_t)NN * DIN * 2);
    unsigned short* BTp  = (unsigned short*)alloc((size_t)DH * DIN * 2);
    unsigned short* BT0  = (unsigned short*)alloc((size_t)DCAT * DH * 2);
    unsigned short* BT1  = (unsigned short*)alloc((size_t)DCAT * DCAT * 2);
    unsigned short* BT2  = (unsigned short*)alloc((size_t)DCAT * DCAT * 2);
    unsigned short* Whb  = (unsigned short*)alloc((size_t)NN * DCAT * 2);
    unsigned short* hb0  = (unsigned short*)alloc((size_t)NN * DCAT * 2);
    unsigned short* hb1  = (unsigned short*)alloc((size_t)NN * DCAT * 2);
    int*   rowptr = (int*)alloc((NN + 1) * 4);
    int*   cursor = (int*)alloc(NN * 4);
    int*   cdst   = (int*)alloc((size_t)EE * 4);
    float* ps    = (float*)alloc(NN * 4);
    float* paw   = (float*)alloc(NN * 4);

    const int* srcp = ei;
    const int* dstp = ei + EE;

    hipMemsetAsync(base + zero_begin, 0, zero_bytes, stream);

    // CSR build
    count_kernel<<<EE / 256, 256, 0, stream>>>(srcp, counts);
    scan_kernel<<<1, 1024, 0, stream>>>(counts, rowptr, cursor);
    fill_kernel<<<EE / 256, 256, 0, stream>>>(srcp, dstp, cursor, cdst);

    // casts / repacks
    cast_kernel<<<(NN * DIN / 4 + 255) / 256, 256, 0, stream>>>(x, xb, NN * DIN / 4);
    transpose_cast_kernel<<<dim3(DIN / 32, 8, 1), 256, 0, stream>>>(Wp, BTp, DIN);
    transpose_cast_kernel<<<dim3(DH / 32, 8, HH), 256, 0, stream>>>(W[0], BT0, DH);
    transpose_cast2_kernel<<<dim3(DCAT / 32, 8, 8), 256, 0, stream>>>(W[1], W[2], BT1, BT2);

    // projection: hb0[N][256] = relu(x @ Wp + bp)
    mfma_gemm_kernel<<<dim3(NN / 128, DH / 128), 256, 0, stream>>>(
        xb, BTp, DIN, hb0, DH, bp, 1, nullptr, nullptr, nullptr, nullptr);

    unsigned short* cur = hb0;
    unsigned short* nxt = hb1;
    const unsigned short* BTl[3] = {BT0, BT1, BT2};
    for (int layer = 0; layer < 3; ++layer) {
        int K = (layer == 0) ? DH : DCAT;
        float* es = es4_3 + (size_t)layer * NN * 4;
        float* ed = ed4_3 + (size_t)layer * NN * 4;
        float* csum = csum3 + (size_t)layer * DCAT;
        mfma_gemm_kernel<<<dim3(NN / 128, DCAT / 128), 256, 0, stream>>>(
            cur, BTl[layer], K, Whb, DCAT, nullptr, 0, av[layer], es, ed, csum);
        agg_kernel<<<NN, 256, 0, stream>>>(Whb, (const f32x4*)es, (const f32x4*)ed,
                                           csum, rowptr, cdst, imp, Ctot, nxt);
        unsigned short* t = cur; cur = nxt; nxt = t;
    }

    // pooling + classifier on bf16 h3 (cur)
    pool_score_kernel<<<NN / 4, 256, 0, stream>>>(cur, pw, pb, ps);
    softmax_n_kernel<<<1, 1024, 0, stream>>>(ps, paw);
    emb_kernel<<<dim3(DCAT / 256, NN / 256), 256, 0, stream>>>(cur, paw, emb);
    c1_kernel<<<32, 256, 0, stream>>>(emb, c1w, zbuf);
    c2_kernel<<<1, 256, 0, stream>>>(zbuf, c1b, c2w, c2b, out);
    natt_kernel<<<NN / 256, 256, 0, stream>>>(imp, Ctot, out);
}